// Round 1
// baseline (869.543 us; speedup 1.0000x reference)
//
#include <hip/hip_runtime.h>
#include <cstdint>
#include <cstddef>

constexpr int N = 50000;
constexpr int E = 800000;
constexpr int D = 256;
constexpr float EPS = 1e-5f;
constexpr int NB = (N + 255) / 256;   // 196 scan blocks

// ---------------- edge-index dtype detection ----------------
// JAX may hand us int32 (x64 disabled, the default) or int64. For int64
// little-endian values < 2^31, every odd 32-bit word is zero. Sample the
// first 1024 odd words; all-zero => int64.
__global__ void k_detect(const void* __restrict__ ei, int* __restrict__ flag) {
  int t = threadIdx.x;  // 64 threads, one wave
  const int* p = (const int*)ei;
  int nz = 0;
  for (int i = 2 * t + 1; i < 2048; i += 128) nz |= (p[i] != 0);
  unsigned long long b = __ballot(nz != 0);
  if (t == 0) *flag = (b == 0ULL) ? 1 : 0;
}

__device__ __forceinline__ int edge_at(const void* ei, int is64, long long pos) {
  if (is64) return (int)((const long long*)ei)[pos];
  return ((const int*)ei)[pos];
}

// ---------------- degree count ----------------
__global__ void k_count(const void* __restrict__ ei, const int* __restrict__ flag,
                        int* __restrict__ degc) {
  int e = blockIdx.x * 256 + threadIdx.x;
  if (e >= E) return;
  int is64 = *flag;
  int c = edge_at(ei, is64, (long long)E + e);
  atomicAdd(&degc[c], 1);
}

// dinv[i] = rsqrt(deg_in[i] + 1)   (self loop included)
__global__ void k_dinv(const int* __restrict__ degc, float* __restrict__ dinv) {
  int i = blockIdx.x * 256 + threadIdx.x;
  if (i >= N) return;
  dinv[i] = rsqrtf((float)(degc[i] + 1));
}

// ---------------- exclusive scan of (degc[i]+1) ----------------
__global__ void k_scan_partial(const int* __restrict__ degc, int* __restrict__ bsum) {
  __shared__ int sd[256];
  int t = threadIdx.x;
  int i = blockIdx.x * 256 + t;
  int v = (i < N) ? (degc[i] + 1) : 0;
  sd[t] = v;
  __syncthreads();
  for (int s = 128; s > 0; s >>= 1) {
    if (t < s) sd[t] += sd[t + s];
    __syncthreads();
  }
  if (t == 0) bsum[blockIdx.x] = sd[0];
}

__global__ void k_scan_block(int* __restrict__ bsum) {
  __shared__ int sd[256];
  int t = threadIdx.x;
  int v = (t < NB) ? bsum[t] : 0;
  sd[t] = v;
  __syncthreads();
  for (int off = 1; off < 256; off <<= 1) {
    int x = (t >= off) ? sd[t - off] : 0;
    __syncthreads();
    sd[t] += x;
    __syncthreads();
  }
  if (t < NB) bsum[t] = sd[t] - v;  // exclusive
}

__global__ void k_scan_final(const int* __restrict__ degc, const int* __restrict__ bsum,
                             int* __restrict__ offs) {
  __shared__ int sd[256];
  int t = threadIdx.x;
  int i = blockIdx.x * 256 + t;
  int v = (i < N) ? (degc[i] + 1) : 0;
  sd[t] = v;
  __syncthreads();
  for (int off = 1; off < 256; off <<= 1) {
    int x = (t >= off) ? sd[t - off] : 0;
    __syncthreads();
    sd[t] += x;
    __syncthreads();
  }
  if (i < N) offs[i] = bsum[blockIdx.x] + sd[t] - v;
  if (i == N - 1) offs[N] = bsum[blockIdx.x] + sd[t];  // total = E + N
}

// ---------------- CSR fill ----------------
// Self loop goes first in each node's slab; cursor starts after it.
__global__ void k_fill_self(const int* __restrict__ offs, const float* __restrict__ dinv,
                            int* __restrict__ curs, int* __restrict__ esrc,
                            float* __restrict__ enrm) {
  int i = blockIdx.x * 256 + threadIdx.x;
  if (i >= N) return;
  int o = offs[i];
  curs[i] = o + 1;
  esrc[o] = i;
  float d = dinv[i];
  enrm[o] = d * d;
}

__global__ void k_fill_edges(const void* __restrict__ ei, const int* __restrict__ flag,
                             const float* __restrict__ dinv, int* __restrict__ curs,
                             int* __restrict__ esrc, float* __restrict__ enrm) {
  int e = blockIdx.x * 256 + threadIdx.x;
  if (e >= E) return;
  int is64 = *flag;
  int r = edge_at(ei, is64, e);
  int c = edge_at(ei, is64, (long long)E + e);
  int p = atomicAdd(&curs[c], 1);
  esrc[p] = r;
  enrm[p] = dinv[r] * dinv[c];
}

// ---------------- GEMM: C[M x 256] = A[M x 256] @ W[256 x 256] ----------------
// BM=64, BN=64, BK=32, 256 threads, 4x4 outputs per thread.
__global__ __launch_bounds__(256) void k_gemm(const float* __restrict__ A,
                                              const float* __restrict__ W,
                                              float* __restrict__ C) {
  __shared__ float As[32][68];  // [k][m], padded: row stride 272B (16B aligned)
  __shared__ float Ws[32][64];  // [k][n]
  int t = threadIdx.x;
  int tx = t & 15;   // n-dim
  int ty = t >> 4;   // m-dim
  int row0 = blockIdx.x * 64;
  int col0 = blockIdx.y * 64;

  float acc[4][4] = {};

  for (int k0 = 0; k0 < 256; k0 += 32) {
    // A tile: 64 rows x 32 cols
#pragma unroll
    for (int l = 0; l < 8; ++l) {
      int idx = t + l * 256;
      int r = idx >> 5;
      int c = idx & 31;
      int gr = row0 + r;
      float v = (gr < N) ? A[(size_t)gr * 256 + k0 + c] : 0.f;
      As[c][r] = v;
    }
    // W tile: 32 rows x 64 cols
#pragma unroll
    for (int l = 0; l < 8; ++l) {
      int idx = t + l * 256;
      int kr = idx >> 6;
      int jc = idx & 63;
      Ws[kr][jc] = W[(size_t)(k0 + kr) * 256 + col0 + jc];
    }
    __syncthreads();
#pragma unroll
    for (int k = 0; k < 32; ++k) {
      float4 a = *(const float4*)&As[k][ty * 4];
      float4 b = *(const float4*)&Ws[k][tx * 4];
      acc[0][0] = fmaf(a.x, b.x, acc[0][0]);
      acc[0][1] = fmaf(a.x, b.y, acc[0][1]);
      acc[0][2] = fmaf(a.x, b.z, acc[0][2]);
      acc[0][3] = fmaf(a.x, b.w, acc[0][3]);
      acc[1][0] = fmaf(a.y, b.x, acc[1][0]);
      acc[1][1] = fmaf(a.y, b.y, acc[1][1]);
      acc[1][2] = fmaf(a.y, b.z, acc[1][2]);
      acc[1][3] = fmaf(a.y, b.w, acc[1][3]);
      acc[2][0] = fmaf(a.z, b.x, acc[2][0]);
      acc[2][1] = fmaf(a.z, b.y, acc[2][1]);
      acc[2][2] = fmaf(a.z, b.z, acc[2][2]);
      acc[2][3] = fmaf(a.z, b.w, acc[2][3]);
      acc[3][0] = fmaf(a.w, b.x, acc[3][0]);
      acc[3][1] = fmaf(a.w, b.y, acc[3][1]);
      acc[3][2] = fmaf(a.w, b.z, acc[3][2]);
      acc[3][3] = fmaf(a.w, b.w, acc[3][3]);
    }
    __syncthreads();
  }

#pragma unroll
  for (int i = 0; i < 4; ++i) {
    int gr = row0 + ty * 4 + i;
    if (gr < N) {
      float4 o = {acc[i][0], acc[i][1], acc[i][2], acc[i][3]};
      *(float4*)&C[(size_t)gr * 256 + col0 + tx * 4] = o;
    }
  }
}

// ---------------- aggregation: out[n] = sum_e norm[e]*h[src[e]] + bias ----------------
// One wave per node; lane = one float4 of the 256 features.
__global__ __launch_bounds__(256) void k_agg(const float* __restrict__ h,
                                             const int* __restrict__ offs,
                                             const int* __restrict__ esrc,
                                             const float* __restrict__ enrm,
                                             const float* __restrict__ bias,
                                             float* __restrict__ out) {
  int node = blockIdx.x * 4 + (threadIdx.x >> 6);
  if (node >= N) return;
  int lane = threadIdx.x & 63;
  int e = offs[node];
  int end = offs[node + 1];
  const float4* hv = (const float4*)h;
  float ax = 0.f, ay = 0.f, az = 0.f, aw = 0.f;
  for (; e < end; ++e) {
    int s = esrc[e];
    float w = enrm[e];
    float4 v = hv[(size_t)s * 64 + lane];
    ax = fmaf(w, v.x, ax);
    ay = fmaf(w, v.y, ay);
    az = fmaf(w, v.z, az);
    aw = fmaf(w, v.w, aw);
  }
  float4 bb = ((const float4*)bias)[lane];
  float4 o = {ax + bb.x, ay + bb.y, az + bb.z, aw + bb.w};
  ((float4*)out)[(size_t)node * 64 + lane] = o;
}

// ---------------- BatchNorm stats: column sum / sumsq ----------------
__global__ __launch_bounds__(256) void k_bnstat(const float* __restrict__ x,
                                                float* __restrict__ sum,
                                                float* __restrict__ sq) {
  int t = threadIdx.x;
  int lane = t & 63;   // float4 column group
  int sub = t >> 6;    // row phase 0..3
  float sx = 0, sy = 0, sz = 0, sw = 0;
  float qx = 0, qy = 0, qz = 0, qw = 0;
  const float4* xv = (const float4*)x;
  for (int r = blockIdx.x * 4 + sub; r < N; r += gridDim.x * 4) {
    float4 v = xv[(size_t)r * 64 + lane];
    sx += v.x; sy += v.y; sz += v.z; sw += v.w;
    qx = fmaf(v.x, v.x, qx); qy = fmaf(v.y, v.y, qy);
    qz = fmaf(v.z, v.z, qz); qw = fmaf(v.w, v.w, qw);
  }
  __shared__ float4 ps[256];
  __shared__ float4 pq[256];
  ps[t] = {sx, sy, sz, sw};
  pq[t] = {qx, qy, qz, qw};
  __syncthreads();
  if (sub == 0) {
    float4 a = ps[lane], b = ps[64 + lane], c = ps[128 + lane], d = ps[192 + lane];
    atomicAdd(&sum[lane * 4 + 0], a.x + b.x + c.x + d.x);
    atomicAdd(&sum[lane * 4 + 1], a.y + b.y + c.y + d.y);
    atomicAdd(&sum[lane * 4 + 2], a.z + b.z + c.z + d.z);
    atomicAdd(&sum[lane * 4 + 3], a.w + b.w + c.w + d.w);
    float4 e = pq[lane], f = pq[64 + lane], g = pq[128 + lane], h2 = pq[192 + lane];
    atomicAdd(&sq[lane * 4 + 0], e.x + f.x + g.x + h2.x);
    atomicAdd(&sq[lane * 4 + 1], e.y + f.y + g.y + h2.y);
    atomicAdd(&sq[lane * 4 + 2], e.z + f.z + g.z + h2.z);
    atomicAdd(&sq[lane * 4 + 3], e.w + f.w + g.w + h2.w);
  }
}

// ---------------- BatchNorm apply + ReLU (in place) ----------------
__global__ __launch_bounds__(256) void k_bnapply(float* __restrict__ x,
                                                 const float* __restrict__ sum,
                                                 const float* __restrict__ sq,
                                                 const float* __restrict__ g,
                                                 const float* __restrict__ be) {
  int t = threadIdx.x;
  int lane = t & 63;
  int sub = t >> 6;
  const float inv = 1.f / (float)N;
  float4 s4 = ((const float4*)sum)[lane];
  float4 q4 = ((const float4*)sq)[lane];
  float4 g4 = ((const float4*)g)[lane];
  float4 b4 = ((const float4*)be)[lane];
  float m0 = s4.x * inv, m1 = s4.y * inv, m2 = s4.z * inv, m3 = s4.w * inv;
  float v0 = q4.x * inv - m0 * m0, v1 = q4.y * inv - m1 * m1;
  float v2 = q4.z * inv - m2 * m2, v3 = q4.w * inv - m3 * m3;
  float sc0 = rsqrtf(v0 + EPS) * g4.x, sc1 = rsqrtf(v1 + EPS) * g4.y;
  float sc2 = rsqrtf(v2 + EPS) * g4.z, sc3 = rsqrtf(v3 + EPS) * g4.w;
  float sh0 = b4.x - m0 * sc0, sh1 = b4.y - m1 * sc1;
  float sh2 = b4.z - m2 * sc2, sh3 = b4.w - m3 * sc3;
  float4* xv = (float4*)x;
  for (int r = blockIdx.x * 4 + sub; r < N; r += gridDim.x * 4) {
    float4 v = xv[(size_t)r * 64 + lane];
    v.x = fmaxf(fmaf(v.x, sc0, sh0), 0.f);
    v.y = fmaxf(fmaf(v.y, sc1, sh1), 0.f);
    v.z = fmaxf(fmaf(v.z, sc2, sh2), 0.f);
    v.w = fmaxf(fmaf(v.w, sc3, sh3), 0.f);
    xv[(size_t)r * 64 + lane] = v;
  }
}

// ---------------- launch ----------------
extern "C" void kernel_launch(void* const* d_in, const int* in_sizes, int n_in,
                              void* d_out, int out_size, void* d_ws, size_t ws_size,
                              hipStream_t stream) {
  const float* x  = (const float*)d_in[0];
  const void*  ei = d_in[1];
  const float* W1 = (const float*)d_in[2];
  const float* b1 = (const float*)d_in[3];
  const float* g1 = (const float*)d_in[4];
  const float* be1 = (const float*)d_in[5];
  const float* W2 = (const float*)d_in[6];
  const float* b2 = (const float*)d_in[7];
  const float* g2 = (const float*)d_in[8];
  const float* be2 = (const float*)d_in[9];
  float* out = (float*)d_out;

  char* base = (char*)d_ws;
  size_t off = 0;
  float* hbuf = (float*)(base + off); off += (size_t)N * D * sizeof(float);
  int*   degc = (int*)(base + off);   off += (size_t)N * 4;
  float* dinv = (float*)(base + off); off += (size_t)N * 4;
  int*   offs = (int*)(base + off);   off += (size_t)(N + 4) * 4;   // keep 16B alignment
  int*   curs = (int*)(base + off);   off += (size_t)N * 4;
  int*   esrc = (int*)(base + off);   off += (size_t)(E + N) * 4;
  float* enrm = (float*)(base + off); off += (size_t)(E + N) * 4;
  float* bnsum = (float*)(base + off); off += (size_t)D * 4;
  float* bnsq  = (float*)(base + off); off += (size_t)D * 4;
  int*   bsum = (int*)(base + off);   off += 256 * 4;
  int*   flag = (int*)(base + off);   off += 16;

  // ---- graph structure (recomputed every call; no cross-call state) ----
  hipMemsetAsync(degc, 0, (size_t)N * 4, stream);
  k_detect<<<1, 64, 0, stream>>>(ei, flag);
  k_count<<<(E + 255) / 256, 256, 0, stream>>>(ei, flag, degc);
  k_dinv<<<NB, 256, 0, stream>>>(degc, dinv);
  k_scan_partial<<<NB, 256, 0, stream>>>(degc, bsum);
  k_scan_block<<<1, 256, 0, stream>>>(bsum);
  k_scan_final<<<NB, 256, 0, stream>>>(degc, bsum, offs);
  k_fill_self<<<NB, 256, 0, stream>>>(offs, dinv, curs, esrc, enrm);
  k_fill_edges<<<(E + 255) / 256, 256, 0, stream>>>(ei, flag, dinv, curs, esrc, enrm);

  dim3 ggrid((N + 63) / 64, D / 64);

  // ---- layer 1 ----
  k_gemm<<<ggrid, 256, 0, stream>>>(x, W1, hbuf);
  k_agg<<<(N + 3) / 4, 256, 0, stream>>>(hbuf, offs, esrc, enrm, b1, out);
  hipMemsetAsync(bnsum, 0, 2 * (size_t)D * 4, stream);  // bnsum+bnsq contiguous
  k_bnstat<<<1024, 256, 0, stream>>>(out, bnsum, bnsq);
  k_bnapply<<<1024, 256, 0, stream>>>(out, bnsum, bnsq, g1, be1);

  // ---- layer 2 ----
  k_gemm<<<ggrid, 256, 0, stream>>>(out, W2, hbuf);
  k_agg<<<(N + 3) / 4, 256, 0, stream>>>(hbuf, offs, esrc, enrm, b2, out);
  hipMemsetAsync(bnsum, 0, 2 * (size_t)D * 4, stream);
  k_bnstat<<<1024, 256, 0, stream>>>(out, bnsum, bnsq);
  k_bnapply<<<1024, 256, 0, stream>>>(out, bnsum, bnsq, g2, be2);
}

// Round 2
// 613.797 us; speedup vs baseline: 1.4167x; 1.4167x over previous
//
#include <hip/hip_runtime.h>
#include <cstdint>
#include <cstddef>

constexpr int N = 50000;
constexpr int E = 800000;
constexpr int D = 256;
constexpr float EPS = 1e-5f;
constexpr int NB = (N + 255) / 256;   // 196 scan blocks
constexpr int BN_BLOCKS = 512;        // stage-A blocks for BN stats

// ---------------- edge-index dtype detection ----------------
// JAX may hand us int32 (x64 disabled, the default) or int64. For int64
// little-endian values < 2^31, every odd 32-bit word is zero. Sample the
// first 1024 odd words; all-zero => int64.
__global__ void k_detect(const void* __restrict__ ei, int* __restrict__ flag) {
  int t = threadIdx.x;  // 64 threads, one wave
  const int* p = (const int*)ei;
  int nz = 0;
  for (int i = 2 * t + 1; i < 2048; i += 128) nz |= (p[i] != 0);
  unsigned long long b = __ballot(nz != 0);
  if (t == 0) *flag = (b == 0ULL) ? 1 : 0;
}

__device__ __forceinline__ int edge_at(const void* ei, int is64, long long pos) {
  if (is64) return (int)((const long long*)ei)[pos];
  return ((const int*)ei)[pos];
}

// ---------------- degree count ----------------
__global__ void k_count(const void* __restrict__ ei, const int* __restrict__ flag,
                        int* __restrict__ degc) {
  int e = blockIdx.x * 256 + threadIdx.x;
  if (e >= E) return;
  int is64 = *flag;
  int c = edge_at(ei, is64, (long long)E + e);
  atomicAdd(&degc[c], 1);
}

// dinv[i] = rsqrt(deg_in[i] + 1)   (self loop included)
__global__ void k_dinv(const int* __restrict__ degc, float* __restrict__ dinv) {
  int i = blockIdx.x * 256 + threadIdx.x;
  if (i >= N) return;
  dinv[i] = rsqrtf((float)(degc[i] + 1));
}

// ---------------- exclusive scan of (degc[i]+1) ----------------
__global__ void k_scan_partial(const int* __restrict__ degc, int* __restrict__ bsum) {
  __shared__ int sd[256];
  int t = threadIdx.x;
  int i = blockIdx.x * 256 + t;
  int v = (i < N) ? (degc[i] + 1) : 0;
  sd[t] = v;
  __syncthreads();
  for (int s = 128; s > 0; s >>= 1) {
    if (t < s) sd[t] += sd[t + s];
    __syncthreads();
  }
  if (t == 0) bsum[blockIdx.x] = sd[0];
}

__global__ void k_scan_block(int* __restrict__ bsum) {
  __shared__ int sd[256];
  int t = threadIdx.x;
  int v = (t < NB) ? bsum[t] : 0;
  sd[t] = v;
  __syncthreads();
  for (int off = 1; off < 256; off <<= 1) {
    int x = (t >= off) ? sd[t - off] : 0;
    __syncthreads();
    sd[t] += x;
    __syncthreads();
  }
  if (t < NB) bsum[t] = sd[t] - v;  // exclusive
}

__global__ void k_scan_final(const int* __restrict__ degc, const int* __restrict__ bsum,
                             int* __restrict__ offs) {
  __shared__ int sd[256];
  int t = threadIdx.x;
  int i = blockIdx.x * 256 + t;
  int v = (i < N) ? (degc[i] + 1) : 0;
  sd[t] = v;
  __syncthreads();
  for (int off = 1; off < 256; off <<= 1) {
    int x = (t >= off) ? sd[t - off] : 0;
    __syncthreads();
    sd[t] += x;
    __syncthreads();
  }
  if (i < N) offs[i] = bsum[blockIdx.x] + sd[t] - v;
  if (i == N - 1) offs[N] = bsum[blockIdx.x] + sd[t];  // total = E + N
}

// ---------------- CSR fill ----------------
// Self loop goes first in each node's slab; cursor starts after it.
__global__ void k_fill_self(const int* __restrict__ offs, const float* __restrict__ dinv,
                            int* __restrict__ curs, int* __restrict__ esrc,
                            float* __restrict__ enrm) {
  int i = blockIdx.x * 256 + threadIdx.x;
  if (i >= N) return;
  int o = offs[i];
  curs[i] = o + 1;
  esrc[o] = i;
  float d = dinv[i];
  enrm[o] = d * d;
}

__global__ void k_fill_edges(const void* __restrict__ ei, const int* __restrict__ flag,
                             const float* __restrict__ dinv, int* __restrict__ curs,
                             int* __restrict__ esrc, float* __restrict__ enrm) {
  int e = blockIdx.x * 256 + threadIdx.x;
  if (e >= E) return;
  int is64 = *flag;
  int r = edge_at(ei, is64, e);
  int c = edge_at(ei, is64, (long long)E + e);
  int p = atomicAdd(&curs[c], 1);
  esrc[p] = r;
  enrm[p] = dinv[r] * dinv[c];
}

// ---------------- GEMM: C[M x 256] = A[M x 256] @ W[256 x 256] ----------------
// BM=64, BN=64, BK=32, 256 threads, 4x4 outputs per thread.
// FUSE_BN: apply per-column affine (sc,sh) + ReLU to A elements at load time
// (this is the previous layer's BatchNorm+ReLU, fused into the A-stage).
template <bool FUSE_BN>
__global__ __launch_bounds__(256) void k_gemm(const float* __restrict__ A,
                                              const float* __restrict__ W,
                                              float* __restrict__ C,
                                              const float* __restrict__ sc,
                                              const float* __restrict__ sh) {
  __shared__ float As[32][68];  // [k][m], padded
  __shared__ float Ws[32][64];  // [k][n]
  int t = threadIdx.x;
  int tx = t & 15;   // n-dim
  int ty = t >> 4;   // m-dim
  int row0 = blockIdx.x * 64;
  int col0 = blockIdx.y * 64;

  float acc[4][4] = {};

  for (int k0 = 0; k0 < 256; k0 += 32) {
    // A tile: 64 rows x 32 cols
#pragma unroll
    for (int l = 0; l < 8; ++l) {
      int idx = t + l * 256;
      int r = idx >> 5;
      int c = idx & 31;
      int gr = row0 + r;
      float v = (gr < N) ? A[(size_t)gr * 256 + k0 + c] : 0.f;
      if (FUSE_BN) v = fmaxf(fmaf(v, sc[k0 + c], sh[k0 + c]), 0.f);
      As[c][r] = v;
    }
    // W tile: 32 rows x 64 cols
#pragma unroll
    for (int l = 0; l < 8; ++l) {
      int idx = t + l * 256;
      int kr = idx >> 6;
      int jc = idx & 63;
      Ws[kr][jc] = W[(size_t)(k0 + kr) * 256 + col0 + jc];
    }
    __syncthreads();
#pragma unroll
    for (int k = 0; k < 32; ++k) {
      float4 a = *(const float4*)&As[k][ty * 4];
      float4 b = *(const float4*)&Ws[k][tx * 4];
      acc[0][0] = fmaf(a.x, b.x, acc[0][0]);
      acc[0][1] = fmaf(a.x, b.y, acc[0][1]);
      acc[0][2] = fmaf(a.x, b.z, acc[0][2]);
      acc[0][3] = fmaf(a.x, b.w, acc[0][3]);
      acc[1][0] = fmaf(a.y, b.x, acc[1][0]);
      acc[1][1] = fmaf(a.y, b.y, acc[1][1]);
      acc[1][2] = fmaf(a.y, b.z, acc[1][2]);
      acc[1][3] = fmaf(a.y, b.w, acc[1][3]);
      acc[2][0] = fmaf(a.z, b.x, acc[2][0]);
      acc[2][1] = fmaf(a.z, b.y, acc[2][1]);
      acc[2][2] = fmaf(a.z, b.z, acc[2][2]);
      acc[2][3] = fmaf(a.z, b.w, acc[2][3]);
      acc[3][0] = fmaf(a.w, b.x, acc[3][0]);
      acc[3][1] = fmaf(a.w, b.y, acc[3][1]);
      acc[3][2] = fmaf(a.w, b.z, acc[3][2]);
      acc[3][3] = fmaf(a.w, b.w, acc[3][3]);
    }
    __syncthreads();
  }

#pragma unroll
  for (int i = 0; i < 4; ++i) {
    int gr = row0 + ty * 4 + i;
    if (gr < N) {
      float4 o = {acc[i][0], acc[i][1], acc[i][2], acc[i][3]};
      *(float4*)&C[(size_t)gr * 256 + col0 + tx * 4] = o;
    }
  }
}

// ---------------- aggregation: out[n] = sum_e norm[e]*h[src[e]] + bias ----------------
// One wave per node; lane = one float4 of the 256 features.
__global__ __launch_bounds__(256) void k_agg(const float* __restrict__ h,
                                             const int* __restrict__ offs,
                                             const int* __restrict__ esrc,
                                             const float* __restrict__ enrm,
                                             const float* __restrict__ bias,
                                             float* __restrict__ out) {
  int node = blockIdx.x * 4 + (threadIdx.x >> 6);
  if (node >= N) return;
  int lane = threadIdx.x & 63;
  int e = offs[node];
  int end = offs[node + 1];
  const float4* hv = (const float4*)h;
  float ax = 0.f, ay = 0.f, az = 0.f, aw = 0.f;
  for (; e < end; ++e) {
    int s = esrc[e];
    float w = enrm[e];
    float4 v = hv[(size_t)s * 64 + lane];
    ax = fmaf(w, v.x, ax);
    ay = fmaf(w, v.y, ay);
    az = fmaf(w, v.z, az);
    aw = fmaf(w, v.w, aw);
  }
  float4 bb = ((const float4*)bias)[lane];
  float4 o = {ax + bb.x, ay + bb.y, az + bb.z, aw + bb.w};
  ((float4*)out)[(size_t)node * 64 + lane] = o;
}

// ---------------- BN stats stage A: per-block partial column sums ----------------
// partial[block][0..255] = sum, partial[block][256..511] = sumsq. No atomics.
__global__ __launch_bounds__(256) void k_bnpart(const float* __restrict__ x,
                                                float* __restrict__ partial) {
  int t = threadIdx.x;
  int lane = t & 63;
  int sub = t >> 6;
  float sx = 0, sy = 0, sz = 0, sw = 0;
  float qx = 0, qy = 0, qz = 0, qw = 0;
  const float4* xv = (const float4*)x;
  for (int r = blockIdx.x * 4 + sub; r < N; r += gridDim.x * 4) {
    float4 v = xv[(size_t)r * 64 + lane];
    sx += v.x; sy += v.y; sz += v.z; sw += v.w;
    qx = fmaf(v.x, v.x, qx); qy = fmaf(v.y, v.y, qy);
    qz = fmaf(v.z, v.z, qz); qw = fmaf(v.w, v.w, qw);
  }
  __shared__ float4 ps[256];
  __shared__ float4 pq[256];
  ps[t] = {sx, sy, sz, sw};
  pq[t] = {qx, qy, qz, qw};
  __syncthreads();
  float* pout = partial + (size_t)blockIdx.x * 512;
  if (t < 64) {
    float4 a = ps[t], b = ps[64 + t], c = ps[128 + t], d = ps[192 + t];
    float4 o = {a.x + b.x + c.x + d.x, a.y + b.y + c.y + d.y,
                a.z + b.z + c.z + d.z, a.w + b.w + c.w + d.w};
    ((float4*)pout)[t] = o;
  } else if (t < 128) {
    int l = t - 64;
    float4 a = pq[l], b = pq[64 + l], c = pq[128 + l], d = pq[192 + l];
    float4 o = {a.x + b.x + c.x + d.x, a.y + b.y + c.y + d.y,
                a.z + b.z + c.z + d.z, a.w + b.w + c.w + d.w};
    ((float4*)(pout + 256))[l] = o;
  }
}

// ---------------- BN stats stage B: reduce partials (16-deep atomics) ----------------
// 16 blocks x 256 threads; block j reduces partial rows [j*32, j*32+32).
__global__ __launch_bounds__(256) void k_bnred(const float* __restrict__ partial,
                                               float* __restrict__ bnsum,
                                               float* __restrict__ bnsq) {
  int t = threadIdx.x;
  float s = 0.f, q = 0.f;
  int b0 = blockIdx.x * (BN_BLOCKS / 16);
  for (int b = b0; b < b0 + BN_BLOCKS / 16; ++b) {
    s += partial[(size_t)b * 512 + t];
    q += partial[(size_t)b * 512 + 256 + t];
  }
  atomicAdd(&bnsum[t], s);
  atomicAdd(&bnsq[t], q);
}

// ---------------- BN finalize: emit per-column scale/shift ----------------
__global__ void k_bnfinal(const float* __restrict__ bnsum, const float* __restrict__ bnsq,
                          const float* __restrict__ g, const float* __restrict__ be,
                          float* __restrict__ sc, float* __restrict__ sh) {
  int t = threadIdx.x;  // 256 threads, 1 block
  const float inv = 1.f / (float)N;
  float m = bnsum[t] * inv;
  float v = bnsq[t] * inv - m * m;
  float s = rsqrtf(v + EPS) * g[t];
  sc[t] = s;
  sh[t] = be[t] - m * s;
}

// ---------------- BN apply + ReLU in place (final output only) ----------------
__global__ __launch_bounds__(256) void k_bnapply(float* __restrict__ x,
                                                 const float* __restrict__ sc,
                                                 const float* __restrict__ sh) {
  int t = threadIdx.x;
  int lane = t & 63;
  int sub = t >> 6;
  float4 s4 = ((const float4*)sc)[lane];
  float4 h4 = ((const float4*)sh)[lane];
  float4* xv = (float4*)x;
  for (int r = blockIdx.x * 4 + sub; r < N; r += gridDim.x * 4) {
    float4 v = xv[(size_t)r * 64 + lane];
    v.x = fmaxf(fmaf(v.x, s4.x, h4.x), 0.f);
    v.y = fmaxf(fmaf(v.y, s4.y, h4.y), 0.f);
    v.z = fmaxf(fmaf(v.z, s4.z, h4.z), 0.f);
    v.w = fmaxf(fmaf(v.w, s4.w, h4.w), 0.f);
    xv[(size_t)r * 64 + lane] = v;
  }
}

// ---------------- launch ----------------
extern "C" void kernel_launch(void* const* d_in, const int* in_sizes, int n_in,
                              void* d_out, int out_size, void* d_ws, size_t ws_size,
                              hipStream_t stream) {
  const float* x  = (const float*)d_in[0];
  const void*  ei = d_in[1];
  const float* W1 = (const float*)d_in[2];
  const float* b1 = (const float*)d_in[3];
  const float* g1 = (const float*)d_in[4];
  const float* be1 = (const float*)d_in[5];
  const float* W2 = (const float*)d_in[6];
  const float* b2 = (const float*)d_in[7];
  const float* g2 = (const float*)d_in[8];
  const float* be2 = (const float*)d_in[9];
  float* out = (float*)d_out;

  char* base = (char*)d_ws;
  size_t off = 0;
  float* hbuf = (float*)(base + off); off += (size_t)N * D * sizeof(float);
  int*   degc = (int*)(base + off);   off += (size_t)N * 4;
  float* dinv = (float*)(base + off); off += (size_t)N * 4;
  int*   offs = (int*)(base + off);   off += (size_t)(N + 4) * 4;
  int*   curs = (int*)(base + off);   off += (size_t)N * 4;
  int*   esrc = (int*)(base + off);   off += (size_t)(E + N) * 4;
  float* enrm = (float*)(base + off); off += (size_t)(E + N) * 4;
  float* partial = (float*)(base + off); off += (size_t)BN_BLOCKS * 512 * 4;  // 1 MB
  float* bnsum = (float*)(base + off); off += (size_t)D * 4;
  float* bnsq  = (float*)(base + off); off += (size_t)D * 4;
  float* sc1 = (float*)(base + off);  off += (size_t)D * 4;
  float* sh1 = (float*)(base + off);  off += (size_t)D * 4;
  float* sc2 = (float*)(base + off);  off += (size_t)D * 4;
  float* sh2 = (float*)(base + off);  off += (size_t)D * 4;
  int*   bsum = (int*)(base + off);   off += 256 * 4;
  int*   flag = (int*)(base + off);   off += 16;

  // ---- graph structure (recomputed every call; no cross-call state) ----
  hipMemsetAsync(degc, 0, (size_t)N * 4, stream);
  k_detect<<<1, 64, 0, stream>>>(ei, flag);
  k_count<<<(E + 255) / 256, 256, 0, stream>>>(ei, flag, degc);
  k_dinv<<<NB, 256, 0, stream>>>(degc, dinv);
  k_scan_partial<<<NB, 256, 0, stream>>>(degc, bsum);
  k_scan_block<<<1, 256, 0, stream>>>(bsum);
  k_scan_final<<<NB, 256, 0, stream>>>(degc, bsum, offs);
  k_fill_self<<<NB, 256, 0, stream>>>(offs, dinv, curs, esrc, enrm);
  k_fill_edges<<<(E + 255) / 256, 256, 0, stream>>>(ei, flag, dinv, curs, esrc, enrm);

  dim3 ggrid((N + 63) / 64, D / 64);

  // ---- layer 1: GEMM -> aggregate -> stats (apply is fused into L2 GEMM) ----
  k_gemm<false><<<ggrid, 256, 0, stream>>>(x, W1, hbuf, nullptr, nullptr);
  k_agg<<<(N + 3) / 4, 256, 0, stream>>>(hbuf, offs, esrc, enrm, b1, out);
  hipMemsetAsync(bnsum, 0, 2 * (size_t)D * 4, stream);  // bnsum+bnsq contiguous
  k_bnpart<<<BN_BLOCKS, 256, 0, stream>>>(out, partial);
  k_bnred<<<16, 256, 0, stream>>>(partial, bnsum, bnsq);
  k_bnfinal<<<1, 256, 0, stream>>>(bnsum, bnsq, g1, be1, sc1, sh1);

  // ---- layer 2: fused(BN1+ReLU) GEMM -> aggregate -> stats -> apply ----
  k_gemm<true><<<ggrid, 256, 0, stream>>>(out, W2, hbuf, sc1, sh1);
  k_agg<<<(N + 3) / 4, 256, 0, stream>>>(hbuf, offs, esrc, enrm, b2, out);
  hipMemsetAsync(bnsum, 0, 2 * (size_t)D * 4, stream);
  k_bnpart<<<BN_BLOCKS, 256, 0, stream>>>(out, partial);
  k_bnred<<<16, 256, 0, stream>>>(partial, bnsum, bnsq);
  k_bnfinal<<<1, 256, 0, stream>>>(bnsum, bnsq, g2, be2, sc2, sh2);
  k_bnapply<<<512, 256, 0, stream>>>(out, sc2, sh2);
}

// Round 3
// 408.921 us; speedup vs baseline: 2.1264x; 1.5010x over previous
//
#include <hip/hip_runtime.h>
#include <cstdint>
#include <cstddef>

constexpr int N = 50000;
constexpr int E = 800000;
constexpr int D = 256;
constexpr float EPS = 1e-5f;
constexpr int NB = (N + 255) / 256;   // 196 scan blocks
constexpr int BN_BLOCKS = 512;        // stage-A blocks for BN stats
constexpr int GB = (N + 63) / 64;     // 782 GEMM blocks

typedef __attribute__((ext_vector_type(8))) short short8;   // 8 bf16 (4 VGPR)
typedef __attribute__((ext_vector_type(4))) float f32x4;    // MFMA acc

// ---- bf16 helpers (RNE) ----
__device__ __forceinline__ unsigned short f2bf(float f) {
  union { float f; unsigned u; } c; c.f = f;
  unsigned u = c.u;
  u += 0x7fff + ((u >> 16) & 1);
  return (unsigned short)(u >> 16);
}
__device__ __forceinline__ float bf2f(unsigned short h) {
  union { unsigned u; float f; } c; c.u = ((unsigned)h) << 16;
  return c.f;
}

// ---------------- edge-index dtype detection ----------------
__global__ void k_detect(const void* __restrict__ ei, int* __restrict__ flag) {
  int t = threadIdx.x;  // 64 threads, one wave
  const int* p = (const int*)ei;
  int nz = 0;
  for (int i = 2 * t + 1; i < 2048; i += 128) nz |= (p[i] != 0);
  unsigned long long b = __ballot(nz != 0);
  if (t == 0) *flag = (b == 0ULL) ? 1 : 0;
}

__device__ __forceinline__ int edge_at(const void* ei, int is64, long long pos) {
  if (is64) return (int)((const long long*)ei)[pos];
  return ((const int*)ei)[pos];
}

// ---------------- degree count ----------------
__global__ void k_count(const void* __restrict__ ei, const int* __restrict__ flag,
                        int* __restrict__ degc) {
  int e = blockIdx.x * 256 + threadIdx.x;
  if (e >= E) return;
  int is64 = *flag;
  int c = edge_at(ei, is64, (long long)E + e);
  atomicAdd(&degc[c], 1);
}

// ---------------- scan stage 1 (+ dinv fused) ----------------
__global__ void k_scan_partial(const int* __restrict__ degc, int* __restrict__ bsum,
                               float* __restrict__ dinv) {
  __shared__ int sd[256];
  int t = threadIdx.x;
  int i = blockIdx.x * 256 + t;
  int dv = (i < N) ? degc[i] : 0;
  if (i < N) dinv[i] = rsqrtf((float)(dv + 1));
  int v = (i < N) ? (dv + 1) : 0;
  sd[t] = v;
  __syncthreads();
  for (int s = 128; s > 0; s >>= 1) {
    if (t < s) sd[t] += sd[t + s];
    __syncthreads();
  }
  if (t == 0) bsum[blockIdx.x] = sd[0];
}

__global__ void k_scan_block(int* __restrict__ bsum) {
  __shared__ int sd[256];
  int t = threadIdx.x;
  int v = (t < NB) ? bsum[t] : 0;
  sd[t] = v;
  __syncthreads();
  for (int off = 1; off < 256; off <<= 1) {
    int x = (t >= off) ? sd[t - off] : 0;
    __syncthreads();
    sd[t] += x;
    __syncthreads();
  }
  if (t < NB) bsum[t] = sd[t] - v;  // exclusive
}

// ---------------- scan stage 3 (+ self-loop fill fused) ----------------
__global__ void k_scan_final(const int* __restrict__ degc, const int* __restrict__ bsum,
                             const float* __restrict__ dinv, int* __restrict__ offs,
                             int* __restrict__ curs, int* __restrict__ esrc,
                             float* __restrict__ enrm) {
  __shared__ int sd[256];
  int t = threadIdx.x;
  int i = blockIdx.x * 256 + t;
  int v = (i < N) ? (degc[i] + 1) : 0;
  sd[t] = v;
  __syncthreads();
  for (int off = 1; off < 256; off <<= 1) {
    int x = (t >= off) ? sd[t - off] : 0;
    __syncthreads();
    sd[t] += x;
    __syncthreads();
  }
  if (i < N) {
    int o = bsum[blockIdx.x] + sd[t] - v;
    offs[i] = o;
    curs[i] = o + 1;
    esrc[o] = i;
    float d = dinv[i];
    enrm[o] = d * d;
  }
  if (i == N - 1) offs[N] = bsum[blockIdx.x] + sd[t];  // total = E + N
}

__global__ void k_fill_edges(const void* __restrict__ ei, const int* __restrict__ flag,
                             const float* __restrict__ dinv, int* __restrict__ curs,
                             int* __restrict__ esrc, float* __restrict__ enrm) {
  int e = blockIdx.x * 256 + threadIdx.x;
  if (e >= E) return;
  int is64 = *flag;
  int r = edge_at(ei, is64, e);
  int c = edge_at(ei, is64, (long long)E + e);
  int p = atomicAdd(&curs[c], 1);
  esrc[p] = r;
  enrm[p] = dinv[r] * dinv[c];
}

// ---------------- W repack: fp32 [256][256] -> bf16 fragment-order ----------------
// Wf[((kstep*16 + wn)*64 + lane)*8 + j] = bf16( W[kstep*32 + (lane>>4)*8 + j][wn*16 + (lane&15)] )
// so a wave's b-frag load is one coalesced 16B read per (kstep, n-frag).
__global__ void k_wfrag(const float* __restrict__ W, unsigned short* __restrict__ Wf) {
  int tile = blockIdx.x;      // 0..127 = kstep*16 + wn
  int lane = threadIdx.x;     // 64
  int kstep = tile >> 4, wn = tile & 15;
  int kbase = kstep * 32 + (lane >> 4) * 8;
  int col = wn * 16 + (lane & 15);
  short8 v;
#pragma unroll
  for (int j = 0; j < 8; ++j)
    v[j] = (short)f2bf(W[(size_t)(kbase + j) * 256 + col]);
  *(short8*)&Wf[(((size_t)tile) * 64 + lane) * 8] = v;
}

// ---------------- MFMA GEMM: C[N x 256](bf16) = A[N x 256](fp32) @ W ----------------
// 256 threads = 4 waves; block tile 64 rows x 256 cols; wave w -> cols w*64..+63.
// K loop: 8 steps of 32. A staged in LDS (bf16, +8 pad); B frags direct from Wf (L2).
// FUSE_BN: apply previous layer's BN affine + ReLU to A at stage time.
template <bool FUSE_BN>
__global__ __launch_bounds__(256) void k_gemm(const float* __restrict__ A,
                                              const unsigned short* __restrict__ Wf,
                                              unsigned short* __restrict__ C,
                                              const float* __restrict__ sc,
                                              const float* __restrict__ sh) {
  __shared__ unsigned short As[64][40];    // [m][k], row stride 80B
  __shared__ unsigned short Cs[64][264];   // epilogue repack, row stride 528B
  int t = threadIdx.x;
  int lane = t & 63;
  int w = t >> 6;
  int row0 = blockIdx.x * 64;
  int l16 = lane & 15, lk = lane >> 4;

  f32x4 acc[4][4];
#pragma unroll
  for (int i = 0; i < 4; ++i)
#pragma unroll
    for (int j = 0; j < 4; ++j) acc[i][j] = (f32x4){0.f, 0.f, 0.f, 0.f};

  int arow = t >> 2;          // 0..63
  int akc = (t & 3) * 8;      // 0,8,16,24

  for (int ks = 0; ks < 8; ++ks) {
    // ---- stage A tile: 64 rows x 32 k (fp32 -> bf16) ----
    {
      int gr = row0 + arow;
      float4 f0 = {0.f, 0.f, 0.f, 0.f}, f1 = {0.f, 0.f, 0.f, 0.f};
      if (gr < N) {
        f0 = *(const float4*)&A[(size_t)gr * 256 + ks * 32 + akc];
        f1 = *(const float4*)&A[(size_t)gr * 256 + ks * 32 + akc + 4];
      }
      if (FUSE_BN) {
        float4 s0 = *(const float4*)&sc[ks * 32 + akc];
        float4 s1 = *(const float4*)&sc[ks * 32 + akc + 4];
        float4 h0 = *(const float4*)&sh[ks * 32 + akc];
        float4 h1 = *(const float4*)&sh[ks * 32 + akc + 4];
        f0.x = fmaxf(fmaf(f0.x, s0.x, h0.x), 0.f);
        f0.y = fmaxf(fmaf(f0.y, s0.y, h0.y), 0.f);
        f0.z = fmaxf(fmaf(f0.z, s0.z, h0.z), 0.f);
        f0.w = fmaxf(fmaf(f0.w, s0.w, h0.w), 0.f);
        f1.x = fmaxf(fmaf(f1.x, s1.x, h1.x), 0.f);
        f1.y = fmaxf(fmaf(f1.y, s1.y, h1.y), 0.f);
        f1.z = fmaxf(fmaf(f1.z, s1.z, h1.z), 0.f);
        f1.w = fmaxf(fmaf(f1.w, s1.w, h1.w), 0.f);
      }
      ushort4 u0 = {f2bf(f0.x), f2bf(f0.y), f2bf(f0.z), f2bf(f0.w)};
      ushort4 u1 = {f2bf(f1.x), f2bf(f1.y), f2bf(f1.z), f2bf(f1.w)};
      *(ushort4*)&As[arow][akc] = u0;
      *(ushort4*)&As[arow][akc + 4] = u1;
    }
    __syncthreads();

    // ---- fragments + MFMA ----
    short8 af[4];
#pragma unroll
    for (int mf = 0; mf < 4; ++mf)
      af[mf] = *(const short8*)&As[mf * 16 + l16][lk * 8];
#pragma unroll
    for (int nf = 0; nf < 4; ++nf) {
      short8 bf = *(const short8*)&Wf[(((size_t)ks * 16 + w * 4 + nf) * 64 + lane) * 8];
#pragma unroll
      for (int mf = 0; mf < 4; ++mf)
        acc[mf][nf] = __builtin_amdgcn_mfma_f32_16x16x32_bf16(af[mf], bf, acc[mf][nf], 0, 0, 0);
    }
    __syncthreads();
  }

  // ---- epilogue: acc -> Cs (bf16) -> coalesced global write ----
#pragma unroll
  for (int mf = 0; mf < 4; ++mf)
#pragma unroll
    for (int nf = 0; nf < 4; ++nf)
#pragma unroll
      for (int r = 0; r < 4; ++r)
        Cs[mf * 16 + lk * 4 + r][w * 64 + nf * 16 + l16] = f2bf(acc[mf][nf][r]);
  __syncthreads();
#pragma unroll
  for (int it = 0; it < 8; ++it) {
    int r = it * 8 + (t >> 5);
    int gr = row0 + r;
    if (gr < N)
      *(short8*)&C[(size_t)gr * 256 + (t & 31) * 8] = *(const short8*)&Cs[r][(t & 31) * 8];
  }
}

// ---------------- aggregation: out[n] = sum_e norm[e]*h[src[e]] + bias ----------------
// One wave per node; lane = 4 bf16 (8B) of the 256 features; fp32 accumulate.
__global__ __launch_bounds__(256) void k_agg(const unsigned short* __restrict__ h,
                                             const int* __restrict__ offs,
                                             const int* __restrict__ esrc,
                                             const float* __restrict__ enrm,
                                             const float* __restrict__ bias,
                                             float* __restrict__ out) {
  int node = blockIdx.x * 4 + (threadIdx.x >> 6);
  if (node >= N) return;
  int lane = threadIdx.x & 63;
  int e = offs[node];
  int end = offs[node + 1];
  float a0 = 0.f, a1 = 0.f, a2 = 0.f, a3 = 0.f;
  for (; e < end; ++e) {
    int s = esrc[e];
    float wgt = enrm[e];
    uint2 v = *(const uint2*)&h[(size_t)s * 256 + lane * 4];
    float f0 = bf2f((unsigned short)(v.x & 0xffff));
    float f1 = bf2f((unsigned short)(v.x >> 16));
    float f2 = bf2f((unsigned short)(v.y & 0xffff));
    float f3 = bf2f((unsigned short)(v.y >> 16));
    a0 = fmaf(wgt, f0, a0);
    a1 = fmaf(wgt, f1, a1);
    a2 = fmaf(wgt, f2, a2);
    a3 = fmaf(wgt, f3, a3);
  }
  float4 bb = ((const float4*)bias)[lane];
  float4 o = {a0 + bb.x, a1 + bb.y, a2 + bb.z, a3 + bb.w};
  *(float4*)&out[(size_t)node * 256 + lane * 4] = o;
}

// ---------------- BN stats stage A: per-block partial column sums ----------------
__global__ __launch_bounds__(256) void k_bnpart(const float* __restrict__ x,
                                                float* __restrict__ partial) {
  int t = threadIdx.x;
  int lane = t & 63;
  int sub = t >> 6;
  float sx = 0, sy = 0, sz = 0, sw = 0;
  float qx = 0, qy = 0, qz = 0, qw = 0;
  const float4* xv = (const float4*)x;
  for (int r = blockIdx.x * 4 + sub; r < N; r += gridDim.x * 4) {
    float4 v = xv[(size_t)r * 64 + lane];
    sx += v.x; sy += v.y; sz += v.z; sw += v.w;
    qx = fmaf(v.x, v.x, qx); qy = fmaf(v.y, v.y, qy);
    qz = fmaf(v.z, v.z, qz); qw = fmaf(v.w, v.w, qw);
  }
  __shared__ float4 ps[256];
  __shared__ float4 pq[256];
  ps[t] = {sx, sy, sz, sw};
  pq[t] = {qx, qy, qz, qw};
  __syncthreads();
  float* pout = partial + (size_t)blockIdx.x * 512;
  if (t < 64) {
    float4 a = ps[t], b = ps[64 + t], c = ps[128 + t], d = ps[192 + t];
    float4 o = {a.x + b.x + c.x + d.x, a.y + b.y + c.y + d.y,
                a.z + b.z + c.z + d.z, a.w + b.w + c.w + d.w};
    ((float4*)pout)[t] = o;
  } else if (t < 128) {
    int l = t - 64;
    float4 a = pq[l], b = pq[64 + l], c = pq[128 + l], d = pq[192 + l];
    float4 o = {a.x + b.x + c.x + d.x, a.y + b.y + c.y + d.y,
                a.z + b.z + c.z + d.z, a.w + b.w + c.w + d.w};
    ((float4*)(pout + 256))[l] = o;
  }
}

// ---------------- BN stats stage B: reduce partials (16-deep atomics) ----------------
__global__ __launch_bounds__(256) void k_bnred(const float* __restrict__ partial,
                                               float* __restrict__ bnsum,
                                               float* __restrict__ bnsq) {
  int t = threadIdx.x;
  float s = 0.f, q = 0.f;
  int b0 = blockIdx.x * (BN_BLOCKS / 16);
  for (int b = b0; b < b0 + BN_BLOCKS / 16; ++b) {
    s += partial[(size_t)b * 512 + t];
    q += partial[(size_t)b * 512 + 256 + t];
  }
  atomicAdd(&bnsum[t], s);
  atomicAdd(&bnsq[t], q);
}

// ---------------- BN finalize: emit per-column scale/shift ----------------
__global__ void k_bnfinal(const float* __restrict__ bnsum, const float* __restrict__ bnsq,
                          const float* __restrict__ g, const float* __restrict__ be,
                          float* __restrict__ sc, float* __restrict__ sh) {
  int t = threadIdx.x;  // 256 threads, 1 block
  const float inv = 1.f / (float)N;
  float m = bnsum[t] * inv;
  float v = bnsq[t] * inv - m * m;
  float s = rsqrtf(v + EPS) * g[t];
  sc[t] = s;
  sh[t] = be[t] - m * s;
}

// ---------------- BN apply + ReLU in place (final output only) ----------------
__global__ __launch_bounds__(256) void k_bnapply(float* __restrict__ x,
                                                 const float* __restrict__ sc,
                                                 const float* __restrict__ sh) {
  int t = threadIdx.x;
  int lane = t & 63;
  int sub = t >> 6;
  float4 s4 = ((const float4*)sc)[lane];
  float4 h4 = ((const float4*)sh)[lane];
  float4* xv = (float4*)x;
  for (int r = blockIdx.x * 4 + sub; r < N; r += gridDim.x * 4) {
    float4 v = xv[(size_t)r * 64 + lane];
    v.x = fmaxf(fmaf(v.x, s4.x, h4.x), 0.f);
    v.y = fmaxf(fmaf(v.y, s4.y, h4.y), 0.f);
    v.z = fmaxf(fmaf(v.z, s4.z, h4.z), 0.f);
    v.w = fmaxf(fmaf(v.w, s4.w, h4.w), 0.f);
    xv[(size_t)r * 64 + lane] = v;
  }
}

// ---------------- launch ----------------
extern "C" void kernel_launch(void* const* d_in, const int* in_sizes, int n_in,
                              void* d_out, int out_size, void* d_ws, size_t ws_size,
                              hipStream_t stream) {
  const float* x  = (const float*)d_in[0];
  const void*  ei = d_in[1];
  const float* W1 = (const float*)d_in[2];
  const float* b1 = (const float*)d_in[3];
  const float* g1 = (const float*)d_in[4];
  const float* be1 = (const float*)d_in[5];
  const float* W2 = (const float*)d_in[6];
  const float* b2 = (const float*)d_in[7];
  const float* g2 = (const float*)d_in[8];
  const float* be2 = (const float*)d_in[9];
  float* out = (float*)d_out;

  char* base = (char*)d_ws;
  size_t off = 0;
  unsigned short* hbuf = (unsigned short*)(base + off); off += (size_t)N * D * 2;  // bf16
  unsigned short* Wf1 = (unsigned short*)(base + off);  off += (size_t)D * D * 2;
  unsigned short* Wf2 = (unsigned short*)(base + off);  off += (size_t)D * D * 2;
  int*   degc = (int*)(base + off);   off += (size_t)N * 4;
  float* dinv = (float*)(base + off); off += (size_t)N * 4;
  int*   offs = (int*)(base + off);   off += (size_t)(N + 4) * 4;
  int*   curs = (int*)(base + off);   off += (size_t)N * 4;
  int*   esrc = (int*)(base + off);   off += (size_t)(E + N) * 4;
  float* enrm = (float*)(base + off); off += (size_t)(E + N) * 4;
  float* partial = (float*)(base + off); off += (size_t)BN_BLOCKS * 512 * 4;  // 1 MB
  float* bnsum = (float*)(base + off); off += (size_t)D * 4;
  float* bnsq  = (float*)(base + off); off += (size_t)D * 4;
  float* sc1 = (float*)(base + off);  off += (size_t)D * 4;
  float* sh1 = (float*)(base + off);  off += (size_t)D * 4;
  float* sc2 = (float*)(base + off);  off += (size_t)D * 4;
  float* sh2 = (float*)(base + off);  off += (size_t)D * 4;
  int*   bsum = (int*)(base + off);   off += 256 * 4;
  int*   flag = (int*)(base + off);   off += 16;

  // ---- W repack (independent of graph build) ----
  k_wfrag<<<128, 64, 0, stream>>>(W1, Wf1);
  k_wfrag<<<128, 64, 0, stream>>>(W2, Wf2);

  // ---- graph structure ----
  hipMemsetAsync(degc, 0, (size_t)N * 4, stream);
  k_detect<<<1, 64, 0, stream>>>(ei, flag);
  k_count<<<(E + 255) / 256, 256, 0, stream>>>(ei, flag, degc);
  k_scan_partial<<<NB, 256, 0, stream>>>(degc, bsum, dinv);
  k_scan_block<<<1, 256, 0, stream>>>(bsum);
  k_scan_final<<<NB, 256, 0, stream>>>(degc, bsum, dinv, offs, curs, esrc, enrm);
  k_fill_edges<<<(E + 255) / 256, 256, 0, stream>>>(ei, flag, dinv, curs, esrc, enrm);

  // ---- layer 1: GEMM -> aggregate -> stats (apply fused into L2 GEMM) ----
  k_gemm<false><<<GB, 256, 0, stream>>>(x, Wf1, hbuf, nullptr, nullptr);
  k_agg<<<(N + 3) / 4, 256, 0, stream>>>(hbuf, offs, esrc, enrm, b1, out);
  hipMemsetAsync(bnsum, 0, 2 * (size_t)D * 4, stream);  // bnsum+bnsq contiguous
  k_bnpart<<<BN_BLOCKS, 256, 0, stream>>>(out, partial);
  k_bnred<<<16, 256, 0, stream>>>(partial, bnsum, bnsq);
  k_bnfinal<<<1, 256, 0, stream>>>(bnsum, bnsq, g1, be1, sc1, sh1);

  // ---- layer 2: fused(BN1+ReLU) GEMM -> aggregate -> stats -> apply ----
  k_gemm<true><<<GB, 256, 0, stream>>>(out, Wf2, hbuf, sc1, sh1);
  k_agg<<<(N + 3) / 4, 256, 0, stream>>>(hbuf, offs, esrc, enrm, b2, out);
  hipMemsetAsync(bnsum, 0, 2 * (size_t)D * 4, stream);
  k_bnpart<<<BN_BLOCKS, 256, 0, stream>>>(out, partial);
  k_bnred<<<16, 256, 0, stream>>>(partial, bnsum, bnsq);
  k_bnfinal<<<1, 256, 0, stream>>>(bnsum, bnsq, g2, be2, sc2, sh2);
  k_bnapply<<<512, 256, 0, stream>>>(out, sc2, sh2);
}

// Round 4
// 324.219 us; speedup vs baseline: 2.6820x; 1.2612x over previous
//
#include <hip/hip_runtime.h>
#include <cstdint>
#include <cstddef>

constexpr int N = 50000;
constexpr int E = 800000;
constexpr int D = 256;
constexpr float EPS = 1e-5f;
constexpr int NB = (N + 255) / 256;   // 196 scan blocks
constexpr int BN_BLOCKS = 512;        // stage-A blocks for BN stats
constexpr int GB = (N + 63) / 64;     // 782 GEMM blocks

typedef __attribute__((ext_vector_type(8))) short short8;   // 8 bf16 (4 VGPR)
typedef __attribute__((ext_vector_type(4))) float f32x4;    // MFMA acc

// ---- bf16 helpers (RNE) ----
__device__ __forceinline__ unsigned short f2bf(float f) {
  union { float f; unsigned u; } c; c.f = f;
  unsigned u = c.u;
  u += 0x7fff + ((u >> 16) & 1);
  return (unsigned short)(u >> 16);
}
__device__ __forceinline__ float bf2f(unsigned short h) {
  union { unsigned u; float f; } c; c.u = ((unsigned)h) << 16;
  return c.f;
}

// ---------------- edge-index dtype detection ----------------
__global__ void k_detect(const void* __restrict__ ei, int* __restrict__ flag) {
  int t = threadIdx.x;  // 64 threads, one wave
  const int* p = (const int*)ei;
  int nz = 0;
  for (int i = 2 * t + 1; i < 2048; i += 128) nz |= (p[i] != 0);
  unsigned long long b = __ballot(nz != 0);
  if (t == 0) *flag = (b == 0ULL) ? 1 : 0;
}

__device__ __forceinline__ int edge_at(const void* ei, int is64, long long pos) {
  if (is64) return (int)((const long long*)ei)[pos];
  return ((const int*)ei)[pos];
}

// ---------------- degree count ----------------
__global__ void k_count(const void* __restrict__ ei, const int* __restrict__ flag,
                        int* __restrict__ degc) {
  int e = blockIdx.x * 256 + threadIdx.x;
  if (e >= E) return;
  int is64 = *flag;
  int c = edge_at(ei, is64, (long long)E + e);
  atomicAdd(&degc[c], 1);
}

// ---------------- scan stage 1 (+ dinv fused) ----------------
__global__ void k_scan_partial(const int* __restrict__ degc, int* __restrict__ bsum,
                               float* __restrict__ dinv) {
  __shared__ int sd[256];
  int t = threadIdx.x;
  int i = blockIdx.x * 256 + t;
  int dv = (i < N) ? degc[i] : 0;
  if (i < N) dinv[i] = rsqrtf((float)(dv + 1));
  int v = (i < N) ? (dv + 1) : 0;
  sd[t] = v;
  __syncthreads();
  for (int s = 128; s > 0; s >>= 1) {
    if (t < s) sd[t] += sd[t + s];
    __syncthreads();
  }
  if (t == 0) bsum[blockIdx.x] = sd[0];
}

__global__ void k_scan_block(int* __restrict__ bsum) {
  __shared__ int sd[256];
  int t = threadIdx.x;
  int v = (t < NB) ? bsum[t] : 0;
  sd[t] = v;
  __syncthreads();
  for (int off = 1; off < 256; off <<= 1) {
    int x = (t >= off) ? sd[t - off] : 0;
    __syncthreads();
    sd[t] += x;
    __syncthreads();
  }
  if (t < NB) bsum[t] = sd[t] - v;  // exclusive
}

// ---------------- scan stage 3 (+ self-loop fill fused) ----------------
__global__ void k_scan_final(const int* __restrict__ degc, const int* __restrict__ bsum,
                             const float* __restrict__ dinv, int* __restrict__ offs,
                             int* __restrict__ curs, int* __restrict__ esrc,
                             float* __restrict__ enrm) {
  __shared__ int sd[256];
  int t = threadIdx.x;
  int i = blockIdx.x * 256 + t;
  int v = (i < N) ? (degc[i] + 1) : 0;
  sd[t] = v;
  __syncthreads();
  for (int off = 1; off < 256; off <<= 1) {
    int x = (t >= off) ? sd[t - off] : 0;
    __syncthreads();
    sd[t] += x;
    __syncthreads();
  }
  if (i < N) {
    int o = bsum[blockIdx.x] + sd[t] - v;
    offs[i] = o;
    curs[i] = o + 1;
    esrc[o] = i;
    float d = dinv[i];
    enrm[o] = d * d;
  }
  if (i == N - 1) offs[N] = bsum[blockIdx.x] + sd[t];  // total = E + N
}

__global__ void k_fill_edges(const void* __restrict__ ei, const int* __restrict__ flag,
                             const float* __restrict__ dinv, int* __restrict__ curs,
                             int* __restrict__ esrc, float* __restrict__ enrm) {
  int e = blockIdx.x * 256 + threadIdx.x;
  if (e >= E) return;
  int is64 = *flag;
  int r = edge_at(ei, is64, e);
  int c = edge_at(ei, is64, (long long)E + e);
  int p = atomicAdd(&curs[c], 1);
  esrc[p] = r;
  enrm[p] = dinv[r] * dinv[c];
}

// ---------------- W repack: fp32 [256][256] -> bf16 fragment-order ----------------
__global__ void k_wfrag(const float* __restrict__ W, unsigned short* __restrict__ Wf) {
  int tile = blockIdx.x;      // 0..127 = kstep*16 + wn
  int lane = threadIdx.x;     // 64
  int kstep = tile >> 4, wn = tile & 15;
  int kbase = kstep * 32 + (lane >> 4) * 8;
  int col = wn * 16 + (lane & 15);
  short8 v;
#pragma unroll
  for (int j = 0; j < 8; ++j)
    v[j] = (short)f2bf(W[(size_t)(kbase + j) * 256 + col]);
  *(short8*)&Wf[(((size_t)tile) * 64 + lane) * 8] = v;
}

// ---------------- MFMA GEMM: C[N x 256](bf16) = A[N x 256] @ W ----------------
// 256 threads = 4 waves; block tile 64 rows x 256 cols; wave w -> cols w*64..+63.
// A_BF16: A is bf16 (row-major); else fp32. FUSE_BN: affine+ReLU at stage time.
template <bool A_BF16, bool FUSE_BN>
__global__ __launch_bounds__(256) void k_gemm(const void* __restrict__ Ap,
                                              const unsigned short* __restrict__ Wf,
                                              unsigned short* __restrict__ C,
                                              const float* __restrict__ sc,
                                              const float* __restrict__ sh) {
  __shared__ unsigned short As[64][40];    // [m][k], row stride 80B
  __shared__ unsigned short Cs[64][264];   // epilogue repack, row stride 528B
  int t = threadIdx.x;
  int lane = t & 63;
  int w = t >> 6;
  int row0 = blockIdx.x * 64;
  int l16 = lane & 15, lk = lane >> 4;

  f32x4 acc[4][4];
#pragma unroll
  for (int i = 0; i < 4; ++i)
#pragma unroll
    for (int j = 0; j < 4; ++j) acc[i][j] = (f32x4){0.f, 0.f, 0.f, 0.f};

  int arow = t >> 2;          // 0..63
  int akc = (t & 3) * 8;      // 0,8,16,24

  for (int ks = 0; ks < 8; ++ks) {
    // ---- stage A tile: 64 rows x 32 k -> bf16 LDS ----
    {
      int gr = row0 + arow;
      float f[8] = {0.f, 0.f, 0.f, 0.f, 0.f, 0.f, 0.f, 0.f};
      if (gr < N) {
        if (A_BF16) {
          const unsigned short* A = (const unsigned short*)Ap;
          short8 v = *(const short8*)&A[(size_t)gr * 256 + ks * 32 + akc];
#pragma unroll
          for (int j = 0; j < 8; ++j) f[j] = bf2f((unsigned short)v[j]);
        } else {
          const float* A = (const float*)Ap;
          float4 f0 = *(const float4*)&A[(size_t)gr * 256 + ks * 32 + akc];
          float4 f1 = *(const float4*)&A[(size_t)gr * 256 + ks * 32 + akc + 4];
          f[0] = f0.x; f[1] = f0.y; f[2] = f0.z; f[3] = f0.w;
          f[4] = f1.x; f[5] = f1.y; f[6] = f1.z; f[7] = f1.w;
        }
      }
      if (FUSE_BN) {
#pragma unroll
        for (int j = 0; j < 8; ++j)
          f[j] = fmaxf(fmaf(f[j], sc[ks * 32 + akc + j], sh[ks * 32 + akc + j]), 0.f);
      }
      ushort4 u0 = {f2bf(f[0]), f2bf(f[1]), f2bf(f[2]), f2bf(f[3])};
      ushort4 u1 = {f2bf(f[4]), f2bf(f[5]), f2bf(f[6]), f2bf(f[7])};
      *(ushort4*)&As[arow][akc] = u0;
      *(ushort4*)&As[arow][akc + 4] = u1;
    }
    __syncthreads();

    // ---- fragments + MFMA ----
    short8 af[4];
#pragma unroll
    for (int mf = 0; mf < 4; ++mf)
      af[mf] = *(const short8*)&As[mf * 16 + l16][lk * 8];
#pragma unroll
    for (int nf = 0; nf < 4; ++nf) {
      short8 bf = *(const short8*)&Wf[(((size_t)ks * 16 + w * 4 + nf) * 64 + lane) * 8];
#pragma unroll
      for (int mf = 0; mf < 4; ++mf)
        acc[mf][nf] = __builtin_amdgcn_mfma_f32_16x16x32_bf16(af[mf], bf, acc[mf][nf], 0, 0, 0);
    }
    __syncthreads();
  }

  // ---- epilogue: acc -> Cs (bf16) -> coalesced global write ----
#pragma unroll
  for (int mf = 0; mf < 4; ++mf)
#pragma unroll
    for (int nf = 0; nf < 4; ++nf)
#pragma unroll
      for (int r = 0; r < 4; ++r)
        Cs[mf * 16 + lk * 4 + r][w * 64 + nf * 16 + l16] = f2bf(acc[mf][nf][r]);
  __syncthreads();
#pragma unroll
  for (int it = 0; it < 8; ++it) {
    int r = it * 8 + (t >> 5);
    int gr = row0 + r;
    if (gr < N)
      *(short8*)&C[(size_t)gr * 256 + (t & 31) * 8] = *(const short8*)&Cs[r][(t & 31) * 8];
  }
}

// ---------------- aggregation: out[n] = sum_e norm[e]*h[src[e]] + bias ----------------
// One wave per node; lane = 4 bf16 (8B); fp32 accumulate; 4-way edge unroll for MLP.
template <bool OUT_BF16>
__global__ __launch_bounds__(256) void k_agg(const unsigned short* __restrict__ h,
                                             const int* __restrict__ offs,
                                             const int* __restrict__ esrc,
                                             const float* __restrict__ enrm,
                                             const float* __restrict__ bias,
                                             void* __restrict__ outp) {
  int nd = blockIdx.x * 4 + (threadIdx.x >> 6);
  if (nd >= N) return;
  int node = __builtin_amdgcn_readfirstlane(nd);  // wave-uniform -> scalar loads
  int lane = threadIdx.x & 63;
  int e = offs[node];
  int end = offs[node + 1];
  float a0 = 0.f, a1 = 0.f, a2 = 0.f, a3 = 0.f;

#define ACC4(v, wgt)                                            \
  do {                                                          \
    a0 = fmaf(wgt, bf2f((unsigned short)((v).x & 0xffff)), a0); \
    a1 = fmaf(wgt, bf2f((unsigned short)((v).x >> 16)), a1);    \
    a2 = fmaf(wgt, bf2f((unsigned short)((v).y & 0xffff)), a2); \
    a3 = fmaf(wgt, bf2f((unsigned short)((v).y >> 16)), a3);    \
  } while (0)

  for (; e + 4 <= end; e += 4) {
    int s0 = esrc[e], s1 = esrc[e + 1], s2 = esrc[e + 2], s3 = esrc[e + 3];
    float w0 = enrm[e], w1 = enrm[e + 1], w2 = enrm[e + 2], w3 = enrm[e + 3];
    uint2 v0 = *(const uint2*)&h[(size_t)s0 * 256 + lane * 4];
    uint2 v1 = *(const uint2*)&h[(size_t)s1 * 256 + lane * 4];
    uint2 v2 = *(const uint2*)&h[(size_t)s2 * 256 + lane * 4];
    uint2 v3 = *(const uint2*)&h[(size_t)s3 * 256 + lane * 4];
    ACC4(v0, w0);
    ACC4(v1, w1);
    ACC4(v2, w2);
    ACC4(v3, w3);
  }
  for (; e < end; ++e) {
    int s = esrc[e];
    float wgt = enrm[e];
    uint2 v = *(const uint2*)&h[(size_t)s * 256 + lane * 4];
    ACC4(v, wgt);
  }
#undef ACC4

  float4 bb = ((const float4*)bias)[lane];
  a0 += bb.x; a1 += bb.y; a2 += bb.z; a3 += bb.w;
  if (OUT_BF16) {
    ushort4 o = {f2bf(a0), f2bf(a1), f2bf(a2), f2bf(a3)};
    *(ushort4*)&((unsigned short*)outp)[(size_t)nd * 256 + lane * 4] = o;
  } else {
    float4 o = {a0, a1, a2, a3};
    *(float4*)&((float*)outp)[(size_t)nd * 256 + lane * 4] = o;
  }
}

// ---------------- BN stats stage A: per-block partial column sums ----------------
template <bool IN_BF16>
__global__ __launch_bounds__(256) void k_bnpart(const void* __restrict__ xp,
                                                float* __restrict__ partial) {
  int t = threadIdx.x;
  int lane = t & 63;
  int sub = t >> 6;
  float sx = 0, sy = 0, sz = 0, sw = 0;
  float qx = 0, qy = 0, qz = 0, qw = 0;
  for (int r = blockIdx.x * 4 + sub; r < N; r += gridDim.x * 4) {
    float4 v;
    if (IN_BF16) {
      uint2 u = *(const uint2*)&((const unsigned short*)xp)[(size_t)r * 256 + lane * 4];
      v.x = bf2f((unsigned short)(u.x & 0xffff));
      v.y = bf2f((unsigned short)(u.x >> 16));
      v.z = bf2f((unsigned short)(u.y & 0xffff));
      v.w = bf2f((unsigned short)(u.y >> 16));
    } else {
      v = *(const float4*)&((const float*)xp)[(size_t)r * 256 + lane * 4];
    }
    sx += v.x; sy += v.y; sz += v.z; sw += v.w;
    qx = fmaf(v.x, v.x, qx); qy = fmaf(v.y, v.y, qy);
    qz = fmaf(v.z, v.z, qz); qw = fmaf(v.w, v.w, qw);
  }
  __shared__ float4 ps[256];
  __shared__ float4 pq[256];
  ps[t] = {sx, sy, sz, sw};
  pq[t] = {qx, qy, qz, qw};
  __syncthreads();
  float* pout = partial + (size_t)blockIdx.x * 512;
  if (t < 64) {
    float4 a = ps[t], b = ps[64 + t], c = ps[128 + t], d = ps[192 + t];
    float4 o = {a.x + b.x + c.x + d.x, a.y + b.y + c.y + d.y,
                a.z + b.z + c.z + d.z, a.w + b.w + c.w + d.w};
    ((float4*)pout)[t] = o;
  } else if (t < 128) {
    int l = t - 64;
    float4 a = pq[l], b = pq[64 + l], c = pq[128 + l], d = pq[192 + l];
    float4 o = {a.x + b.x + c.x + d.x, a.y + b.y + c.y + d.y,
                a.z + b.z + c.z + d.z, a.w + b.w + c.w + d.w};
    ((float4*)(pout + 256))[l] = o;
  }
}

// ---------------- BN stats stage B: reduce partials (16-deep atomics) ----------------
__global__ __launch_bounds__(256) void k_bnred(const float* __restrict__ partial,
                                               float* __restrict__ bnsum,
                                               float* __restrict__ bnsq) {
  int t = threadIdx.x;
  float s = 0.f, q = 0.f;
  int b0 = blockIdx.x * (BN_BLOCKS / 16);
  for (int b = b0; b < b0 + BN_BLOCKS / 16; ++b) {
    s += partial[(size_t)b * 512 + t];
    q += partial[(size_t)b * 512 + 256 + t];
  }
  atomicAdd(&bnsum[t], s);
  atomicAdd(&bnsq[t], q);
}

// ---------------- BN finalize: emit per-column scale/shift ----------------
__global__ void k_bnfinal(const float* __restrict__ bnsum, const float* __restrict__ bnsq,
                          const float* __restrict__ g, const float* __restrict__ be,
                          float* __restrict__ sc, float* __restrict__ sh) {
  int t = threadIdx.x;  // 256 threads, 1 block
  const float inv = 1.f / (float)N;
  float m = bnsum[t] * inv;
  float v = bnsq[t] * inv - m * m;
  float s = rsqrtf(v + EPS) * g[t];
  sc[t] = s;
  sh[t] = be[t] - m * s;
}

// ---------------- BN apply + ReLU in place (final output only) ----------------
__global__ __launch_bounds__(256) void k_bnapply(float* __restrict__ x,
                                                 const float* __restrict__ sc,
                                                 const float* __restrict__ sh) {
  int t = threadIdx.x;
  int lane = t & 63;
  int sub = t >> 6;
  float4 s4 = ((const float4*)sc)[lane];
  float4 h4 = ((const float4*)sh)[lane];
  float4* xv = (float4*)x;
  for (int r = blockIdx.x * 4 + sub; r < N; r += gridDim.x * 4) {
    float4 v = xv[(size_t)r * 64 + lane];
    v.x = fmaxf(fmaf(v.x, s4.x, h4.x), 0.f);
    v.y = fmaxf(fmaf(v.y, s4.y, h4.y), 0.f);
    v.z = fmaxf(fmaf(v.z, s4.z, h4.z), 0.f);
    v.w = fmaxf(fmaf(v.w, s4.w, h4.w), 0.f);
    xv[(size_t)r * 64 + lane] = v;
  }
}

// ---------------- launch ----------------
extern "C" void kernel_launch(void* const* d_in, const int* in_sizes, int n_in,
                              void* d_out, int out_size, void* d_ws, size_t ws_size,
                              hipStream_t stream) {
  const float* x  = (const float*)d_in[0];
  const void*  ei = d_in[1];
  const float* W1 = (const float*)d_in[2];
  const float* b1 = (const float*)d_in[3];
  const float* g1 = (const float*)d_in[4];
  const float* be1 = (const float*)d_in[5];
  const float* W2 = (const float*)d_in[6];
  const float* b2 = (const float*)d_in[7];
  const float* g2 = (const float*)d_in[8];
  const float* be2 = (const float*)d_in[9];
  float* out = (float*)d_out;

  char* base = (char*)d_ws;
  size_t off = 0;
  unsigned short* hbuf = (unsigned short*)(base + off); off += (size_t)N * D * 2;  // bf16
  unsigned short* abuf = (unsigned short*)(base + off); off += (size_t)N * D * 2;  // bf16
  unsigned short* Wf1 = (unsigned short*)(base + off);  off += (size_t)D * D * 2;
  unsigned short* Wf2 = (unsigned short*)(base + off);  off += (size_t)D * D * 2;
  int*   degc = (int*)(base + off);   off += (size_t)N * 4;
  float* dinv = (float*)(base + off); off += (size_t)N * 4;
  int*   offs = (int*)(base + off);   off += (size_t)(N + 4) * 4;
  int*   curs = (int*)(base + off);   off += (size_t)N * 4;
  int*   esrc = (int*)(base + off);   off += (size_t)(E + N) * 4;
  float* enrm = (float*)(base + off); off += (size_t)(E + N) * 4;
  float* partial = (float*)(base + off); off += (size_t)BN_BLOCKS * 512 * 4;  // 1 MB
  float* bnsum = (float*)(base + off); off += (size_t)D * 4;
  float* bnsq  = (float*)(base + off); off += (size_t)D * 4;
  float* sc1 = (float*)(base + off);  off += (size_t)D * 4;
  float* sh1 = (float*)(base + off);  off += (size_t)D * 4;
  float* sc2 = (float*)(base + off);  off += (size_t)D * 4;
  float* sh2 = (float*)(base + off);  off += (size_t)D * 4;
  int*   bsum = (int*)(base + off);   off += 256 * 4;
  int*   flag = (int*)(base + off);   off += 16;

  // ---- W repack (independent of graph build) ----
  k_wfrag<<<128, 64, 0, stream>>>(W1, Wf1);
  k_wfrag<<<128, 64, 0, stream>>>(W2, Wf2);

  // ---- graph structure ----
  hipMemsetAsync(degc, 0, (size_t)N * 4, stream);
  k_detect<<<1, 64, 0, stream>>>(ei, flag);
  k_count<<<(E + 255) / 256, 256, 0, stream>>>(ei, flag, degc);
  k_scan_partial<<<NB, 256, 0, stream>>>(degc, bsum, dinv);
  k_scan_block<<<1, 256, 0, stream>>>(bsum);
  k_scan_final<<<NB, 256, 0, stream>>>(degc, bsum, dinv, offs, curs, esrc, enrm);
  k_fill_edges<<<(E + 255) / 256, 256, 0, stream>>>(ei, flag, dinv, curs, esrc, enrm);

  // ---- layer 1: GEMM -> aggregate(bf16 out) -> stats (apply fused into L2 GEMM) ----
  k_gemm<false, false><<<GB, 256, 0, stream>>>(x, Wf1, hbuf, nullptr, nullptr);
  k_agg<true><<<(N + 3) / 4, 256, 0, stream>>>(hbuf, offs, esrc, enrm, b1, abuf);
  hipMemsetAsync(bnsum, 0, 2 * (size_t)D * 4, stream);  // bnsum+bnsq contiguous
  k_bnpart<true><<<BN_BLOCKS, 256, 0, stream>>>(abuf, partial);
  k_bnred<<<16, 256, 0, stream>>>(partial, bnsum, bnsq);
  k_bnfinal<<<1, 256, 0, stream>>>(bnsum, bnsq, g1, be1, sc1, sh1);

  // ---- layer 2: fused(BN1+ReLU) GEMM -> aggregate -> stats -> apply ----
  k_gemm<true, true><<<GB, 256, 0, stream>>>(abuf, Wf2, hbuf, sc1, sh1);
  k_agg<false><<<(N + 3) / 4, 256, 0, stream>>>(hbuf, offs, esrc, enrm, b2, out);
  hipMemsetAsync(bnsum, 0, 2 * (size_t)D * 4, stream);
  k_bnpart<false><<<BN_BLOCKS, 256, 0, stream>>>(out, partial);
  k_bnred<<<16, 256, 0, stream>>>(partial, bnsum, bnsq);
  k_bnfinal<<<1, 256, 0, stream>>>(bnsum, bnsq, g2, be2, sc2, sh2);
  k_bnapply<<<512, 256, 0, stream>>>(out, sc2, sh2);
}

// Round 5
// 315.407 us; speedup vs baseline: 2.7569x; 1.0279x over previous
//
#include <hip/hip_runtime.h>
#include <cstdint>
#include <cstddef>

constexpr int N = 50000;
constexpr int E = 800000;
constexpr int D = 256;
constexpr float EPS = 1e-5f;
constexpr int NB = (N + 255) / 256;   // 196 scan blocks
constexpr int BN_BLOCKS = 512;        // stage-A blocks for BN stats
constexpr int GB = (N + 63) / 64;     // 782 GEMM blocks

typedef __attribute__((ext_vector_type(8))) short short8;   // 8 bf16 (4 VGPR)
typedef __attribute__((ext_vector_type(4))) float f32x4;    // MFMA acc

// ---- bf16 helpers (RNE) ----
__device__ __forceinline__ unsigned short f2bf(float f) {
  union { float f; unsigned u; } c; c.f = f;
  unsigned u = c.u;
  u += 0x7fff + ((u >> 16) & 1);
  return (unsigned short)(u >> 16);
}
__device__ __forceinline__ float bf2f(unsigned short h) {
  union { unsigned u; float f; } c; c.u = ((unsigned)h) << 16;
  return c.f;
}

// ---------------- edge-index dtype detection ----------------
__global__ void k_detect(const void* __restrict__ ei, int* __restrict__ flag) {
  int t = threadIdx.x;  // 64 threads, one wave
  const int* p = (const int*)ei;
  int nz = 0;
  for (int i = 2 * t + 1; i < 2048; i += 128) nz |= (p[i] != 0);
  unsigned long long b = __ballot(nz != 0);
  if (t == 0) *flag = (b == 0ULL) ? 1 : 0;
}

__device__ __forceinline__ int edge_at(const void* ei, int is64, long long pos) {
  if (is64) return (int)((const long long*)ei)[pos];
  return ((const int*)ei)[pos];
}

// ---------------- degree count ----------------
__global__ void k_count(const void* __restrict__ ei, const int* __restrict__ flag,
                        int* __restrict__ degc) {
  int e = blockIdx.x * 256 + threadIdx.x;
  if (e >= E) return;
  int is64 = *flag;
  int c = edge_at(ei, is64, (long long)E + e);
  atomicAdd(&degc[c], 1);
}

// ---------------- scan stage 1 (+ dinv fused) ----------------
__global__ void k_scan_partial(const int* __restrict__ degc, int* __restrict__ bsum,
                               float* __restrict__ dinv) {
  __shared__ int sd[256];
  int t = threadIdx.x;
  int i = blockIdx.x * 256 + t;
  int dv = (i < N) ? degc[i] : 0;
  if (i < N) dinv[i] = rsqrtf((float)(dv + 1));
  int v = (i < N) ? (dv + 1) : 0;
  sd[t] = v;
  __syncthreads();
  for (int s = 128; s > 0; s >>= 1) {
    if (t < s) sd[t] += sd[t + s];
    __syncthreads();
  }
  if (t == 0) bsum[blockIdx.x] = sd[0];
}

__global__ void k_scan_block(int* __restrict__ bsum) {
  __shared__ int sd[256];
  int t = threadIdx.x;
  int v = (t < NB) ? bsum[t] : 0;
  sd[t] = v;
  __syncthreads();
  for (int off = 1; off < 256; off <<= 1) {
    int x = (t >= off) ? sd[t - off] : 0;
    __syncthreads();
    sd[t] += x;
    __syncthreads();
  }
  if (t < NB) bsum[t] = sd[t] - v;  // exclusive
}

// ---------------- scan stage 3 (+ self-loop fill fused) ----------------
__global__ void k_scan_final(const int* __restrict__ degc, const int* __restrict__ bsum,
                             const float* __restrict__ dinv, int* __restrict__ offs,
                             int* __restrict__ curs, int2* __restrict__ epair) {
  __shared__ int sd[256];
  int t = threadIdx.x;
  int i = blockIdx.x * 256 + t;
  int v = (i < N) ? (degc[i] + 1) : 0;
  sd[t] = v;
  __syncthreads();
  for (int off = 1; off < 256; off <<= 1) {
    int x = (t >= off) ? sd[t - off] : 0;
    __syncthreads();
    sd[t] += x;
    __syncthreads();
  }
  if (i < N) {
    int o = bsum[blockIdx.x] + sd[t] - v;
    offs[i] = o;
    curs[i] = o + 1;
    float d = dinv[i];
    epair[o] = make_int2(i, __float_as_int(d * d));
  }
  if (i == N - 1) offs[N] = bsum[blockIdx.x] + sd[t];  // total = E + N
}

__global__ void k_fill_edges(const void* __restrict__ ei, const int* __restrict__ flag,
                             const float* __restrict__ dinv, int* __restrict__ curs,
                             int2* __restrict__ epair) {
  int e = blockIdx.x * 256 + threadIdx.x;
  if (e >= E) return;
  int is64 = *flag;
  int r = edge_at(ei, is64, e);
  int c = edge_at(ei, is64, (long long)E + e);
  int p = atomicAdd(&curs[c], 1);
  epair[p] = make_int2(r, __float_as_int(dinv[r] * dinv[c]));
}

// ---------------- W repack: fp32 [256][256] -> bf16 fragment-order ----------------
__global__ void k_wfrag(const float* __restrict__ W, unsigned short* __restrict__ Wf) {
  int tile = blockIdx.x;      // 0..127 = kstep*16 + wn
  int lane = threadIdx.x;     // 64
  int kstep = tile >> 4, wn = tile & 15;
  int kbase = kstep * 32 + (lane >> 4) * 8;
  int col = wn * 16 + (lane & 15);
  short8 v;
#pragma unroll
  for (int j = 0; j < 8; ++j)
    v[j] = (short)f2bf(W[(size_t)(kbase + j) * 256 + col]);
  *(short8*)&Wf[(((size_t)tile) * 64 + lane) * 8] = v;
}

// ---------------- MFMA GEMM: C[N x 256](bf16) = A[N x 256] @ W ----------------
// 256 threads = 4 waves; block tile 64 rows x 256 cols; wave w -> cols w*64..+63.
// Full A tile (64x256) staged once -> 3 barriers total. LDS buffer aliased for
// the epilogue repack (write starts only after a barrier past the last ds_read).
template <bool A_BF16, bool FUSE_BN>
__global__ __launch_bounds__(256) void k_gemm(const void* __restrict__ Ap,
                                              const unsigned short* __restrict__ Wf,
                                              unsigned short* __restrict__ C,
                                              const float* __restrict__ sc,
                                              const float* __restrict__ sh) {
  __shared__ unsigned short As[64][264];   // [m][k] +8 pad; reused as Cs[64][264]
  int t = threadIdx.x;
  int lane = t & 63;
  int w = t >> 6;
  int row0 = blockIdx.x * 64;
  int l16 = lane & 15, lk = lane >> 4;

  f32x4 acc[4][4];
#pragma unroll
  for (int i = 0; i < 4; ++i)
#pragma unroll
    for (int j = 0; j < 4; ++j) acc[i][j] = (f32x4){0.f, 0.f, 0.f, 0.f};

  int arow = t >> 2;          // 0..63
  int ak0 = (t & 3) * 8;      // 0,8,16,24
  int gr = row0 + arow;
  bool inb = (gr < N);

  // ---- stage the whole 64x256 A tile (bf16) ----
#pragma unroll
  for (int ks = 0; ks < 8; ++ks) {
    int kc = ks * 32 + ak0;
    float f[8] = {0.f, 0.f, 0.f, 0.f, 0.f, 0.f, 0.f, 0.f};
    if (inb) {
      if (A_BF16) {
        const unsigned short* A = (const unsigned short*)Ap;
        short8 v = *(const short8*)&A[(size_t)gr * 256 + kc];
#pragma unroll
        for (int j = 0; j < 8; ++j) f[j] = bf2f((unsigned short)v[j]);
      } else {
        const float* A = (const float*)Ap;
        float4 f0 = *(const float4*)&A[(size_t)gr * 256 + kc];
        float4 f1 = *(const float4*)&A[(size_t)gr * 256 + kc + 4];
        f[0] = f0.x; f[1] = f0.y; f[2] = f0.z; f[3] = f0.w;
        f[4] = f1.x; f[5] = f1.y; f[6] = f1.z; f[7] = f1.w;
      }
    }
    if (FUSE_BN) {
#pragma unroll
      for (int j = 0; j < 8; ++j)
        f[j] = fmaxf(fmaf(f[j], sc[kc + j], sh[kc + j]), 0.f);
    }
    ushort4 u0 = {f2bf(f[0]), f2bf(f[1]), f2bf(f[2]), f2bf(f[3])};
    ushort4 u1 = {f2bf(f[4]), f2bf(f[5]), f2bf(f[6]), f2bf(f[7])};
    *(ushort4*)&As[arow][kc] = u0;
    *(ushort4*)&As[arow][kc + 4] = u1;
  }
  __syncthreads();

  // ---- main loop: no barriers, ds_read + L2-resident B-frag + MFMA ----
#pragma unroll
  for (int ks = 0; ks < 8; ++ks) {
    short8 af[4];
#pragma unroll
    for (int mf = 0; mf < 4; ++mf)
      af[mf] = *(const short8*)&As[mf * 16 + l16][ks * 32 + lk * 8];
#pragma unroll
    for (int nf = 0; nf < 4; ++nf) {
      short8 bf = *(const short8*)&Wf[(((size_t)ks * 16 + w * 4 + nf) * 64 + lane) * 8];
#pragma unroll
      for (int mf = 0; mf < 4; ++mf)
        acc[mf][nf] = __builtin_amdgcn_mfma_f32_16x16x32_bf16(af[mf], bf, acc[mf][nf], 0, 0, 0);
    }
  }
  __syncthreads();  // As reads done; safe to alias as Cs

  // ---- epilogue: acc -> Cs (bf16) -> coalesced global write ----
  unsigned short(*Cs)[264] = As;
#pragma unroll
  for (int mf = 0; mf < 4; ++mf)
#pragma unroll
    for (int nf = 0; nf < 4; ++nf)
#pragma unroll
      for (int r = 0; r < 4; ++r)
        Cs[mf * 16 + lk * 4 + r][w * 64 + nf * 16 + l16] = f2bf(acc[mf][nf][r]);
  __syncthreads();
#pragma unroll
  for (int it = 0; it < 8; ++it) {
    int r = it * 8 + (t >> 5);
    int gr2 = row0 + r;
    if (gr2 < N)
      *(short8*)&C[(size_t)gr2 * 256 + (t & 31) * 8] = *(const short8*)&Cs[r][(t & 31) * 8];
  }
}

// ---------------- aggregation: out[n] = sum_e nrm[e]*h[src[e]] + bias ----------------
// One wave per node; lane = 4 bf16 (8B); fp32 accumulate; 8-way edge unroll.
// epair[e] = (src, nrm) -> one uniform 8B load per edge; bf16 output.
__global__ __launch_bounds__(256) void k_agg(const unsigned short* __restrict__ h,
                                             const int* __restrict__ offs,
                                             const int2* __restrict__ epair,
                                             const float* __restrict__ bias,
                                             unsigned short* __restrict__ outp) {
  int nd = blockIdx.x * 4 + (threadIdx.x >> 6);
  if (nd >= N) return;
  int node = __builtin_amdgcn_readfirstlane(nd);  // wave-uniform -> scalar loads
  int lane = threadIdx.x & 63;
  int e = offs[node];
  int end = offs[node + 1];
  float a0 = 0.f, a1 = 0.f, a2 = 0.f, a3 = 0.f;

#define ACC4(v, wgt)                                            \
  do {                                                          \
    a0 = fmaf(wgt, bf2f((unsigned short)((v).x & 0xffff)), a0); \
    a1 = fmaf(wgt, bf2f((unsigned short)((v).x >> 16)), a1);    \
    a2 = fmaf(wgt, bf2f((unsigned short)((v).y & 0xffff)), a2); \
    a3 = fmaf(wgt, bf2f((unsigned short)((v).y >> 16)), a3);    \
  } while (0)

  for (; e + 8 <= end; e += 8) {
    int2 p0 = epair[e + 0], p1 = epair[e + 1], p2 = epair[e + 2], p3 = epair[e + 3];
    int2 p4 = epair[e + 4], p5 = epair[e + 5], p6 = epair[e + 6], p7 = epair[e + 7];
    uint2 v0 = *(const uint2*)&h[(size_t)p0.x * 256 + lane * 4];
    uint2 v1 = *(const uint2*)&h[(size_t)p1.x * 256 + lane * 4];
    uint2 v2 = *(const uint2*)&h[(size_t)p2.x * 256 + lane * 4];
    uint2 v3 = *(const uint2*)&h[(size_t)p3.x * 256 + lane * 4];
    uint2 v4 = *(const uint2*)&h[(size_t)p4.x * 256 + lane * 4];
    uint2 v5 = *(const uint2*)&h[(size_t)p5.x * 256 + lane * 4];
    uint2 v6 = *(const uint2*)&h[(size_t)p6.x * 256 + lane * 4];
    uint2 v7 = *(const uint2*)&h[(size_t)p7.x * 256 + lane * 4];
    ACC4(v0, __int_as_float(p0.y));
    ACC4(v1, __int_as_float(p1.y));
    ACC4(v2, __int_as_float(p2.y));
    ACC4(v3, __int_as_float(p3.y));
    ACC4(v4, __int_as_float(p4.y));
    ACC4(v5, __int_as_float(p5.y));
    ACC4(v6, __int_as_float(p6.y));
    ACC4(v7, __int_as_float(p7.y));
  }
  for (; e < end; ++e) {
    int2 p = epair[e];
    uint2 v = *(const uint2*)&h[(size_t)p.x * 256 + lane * 4];
    ACC4(v, __int_as_float(p.y));
  }
#undef ACC4

  float4 bb = ((const float4*)bias)[lane];
  a0 += bb.x; a1 += bb.y; a2 += bb.z; a3 += bb.w;
  ushort4 o = {f2bf(a0), f2bf(a1), f2bf(a2), f2bf(a3)};
  *(ushort4*)&outp[(size_t)nd * 256 + lane * 4] = o;
}

// ---------------- BN stats stage A: per-block partial column sums (bf16 in) ----------------
__global__ __launch_bounds__(256) void k_bnpart(const unsigned short* __restrict__ xp,
                                                float* __restrict__ partial) {
  int t = threadIdx.x;
  int lane = t & 63;
  int sub = t >> 6;
  float sx = 0, sy = 0, sz = 0, sw = 0;
  float qx = 0, qy = 0, qz = 0, qw = 0;
  for (int r = blockIdx.x * 4 + sub; r < N; r += gridDim.x * 4) {
    uint2 u = *(const uint2*)&xp[(size_t)r * 256 + lane * 4];
    float vx = bf2f((unsigned short)(u.x & 0xffff));
    float vy = bf2f((unsigned short)(u.x >> 16));
    float vz = bf2f((unsigned short)(u.y & 0xffff));
    float vw = bf2f((unsigned short)(u.y >> 16));
    sx += vx; sy += vy; sz += vz; sw += vw;
    qx = fmaf(vx, vx, qx); qy = fmaf(vy, vy, qy);
    qz = fmaf(vz, vz, qz); qw = fmaf(vw, vw, qw);
  }
  __shared__ float4 ps[256];
  __shared__ float4 pq[256];
  ps[t] = {sx, sy, sz, sw};
  pq[t] = {qx, qy, qz, qw};
  __syncthreads();
  float* pout = partial + (size_t)blockIdx.x * 512;
  if (t < 64) {
    float4 a = ps[t], b = ps[64 + t], c = ps[128 + t], d = ps[192 + t];
    float4 o = {a.x + b.x + c.x + d.x, a.y + b.y + c.y + d.y,
                a.z + b.z + c.z + d.z, a.w + b.w + c.w + d.w};
    ((float4*)pout)[t] = o;
  } else if (t < 128) {
    int l = t - 64;
    float4 a = pq[l], b = pq[64 + l], c = pq[128 + l], d = pq[192 + l];
    float4 o = {a.x + b.x + c.x + d.x, a.y + b.y + c.y + d.y,
                a.z + b.z + c.z + d.z, a.w + b.w + c.w + d.w};
    ((float4*)(pout + 256))[l] = o;
  }
}

// ---------------- BN stats stage B: reduce partials (16-deep atomics) ----------------
__global__ __launch_bounds__(256) void k_bnred(const float* __restrict__ partial,
                                               float* __restrict__ bnsum,
                                               float* __restrict__ bnsq) {
  int t = threadIdx.x;
  float s = 0.f, q = 0.f;
  int b0 = blockIdx.x * (BN_BLOCKS / 16);
  for (int b = b0; b < b0 + BN_BLOCKS / 16; ++b) {
    s += partial[(size_t)b * 512 + t];
    q += partial[(size_t)b * 512 + 256 + t];
  }
  atomicAdd(&bnsum[t], s);
  atomicAdd(&bnsq[t], q);
}

// ---------------- BN finalize: emit per-column scale/shift ----------------
__global__ void k_bnfinal(const float* __restrict__ bnsum, const float* __restrict__ bnsq,
                          const float* __restrict__ g, const float* __restrict__ be,
                          float* __restrict__ sc, float* __restrict__ sh) {
  int t = threadIdx.x;  // 256 threads, 1 block
  const float inv = 1.f / (float)N;
  float m = bnsum[t] * inv;
  float v = bnsq[t] * inv - m * m;
  float s = rsqrtf(v + EPS) * g[t];
  sc[t] = s;
  sh[t] = be[t] - m * s;
}

// ---------------- BN apply + ReLU: bf16 in -> fp32 out ----------------
__global__ __launch_bounds__(256) void k_bnapply(const unsigned short* __restrict__ in,
                                                 float* __restrict__ outp,
                                                 const float* __restrict__ sc,
                                                 const float* __restrict__ sh) {
  int t = threadIdx.x;
  int lane = t & 63;
  int sub = t >> 6;
  float4 s4 = ((const float4*)sc)[lane];
  float4 h4 = ((const float4*)sh)[lane];
  for (int r = blockIdx.x * 4 + sub; r < N; r += gridDim.x * 4) {
    uint2 u = *(const uint2*)&in[(size_t)r * 256 + lane * 4];
    float4 v;
    v.x = fmaxf(fmaf(bf2f((unsigned short)(u.x & 0xffff)), s4.x, h4.x), 0.f);
    v.y = fmaxf(fmaf(bf2f((unsigned short)(u.x >> 16)), s4.y, h4.y), 0.f);
    v.z = fmaxf(fmaf(bf2f((unsigned short)(u.y & 0xffff)), s4.z, h4.z), 0.f);
    v.w = fmaxf(fmaf(bf2f((unsigned short)(u.y >> 16)), s4.w, h4.w), 0.f);
    *(float4*)&outp[(size_t)r * 256 + lane * 4] = v;
  }
}

// ---------------- launch ----------------
extern "C" void kernel_launch(void* const* d_in, const int* in_sizes, int n_in,
                              void* d_out, int out_size, void* d_ws, size_t ws_size,
                              hipStream_t stream) {
  const float* x  = (const float*)d_in[0];
  const void*  ei = d_in[1];
  const float* W1 = (const float*)d_in[2];
  const float* b1 = (const float*)d_in[3];
  const float* g1 = (const float*)d_in[4];
  const float* be1 = (const float*)d_in[5];
  const float* W2 = (const float*)d_in[6];
  const float* b2 = (const float*)d_in[7];
  const float* g2 = (const float*)d_in[8];
  const float* be2 = (const float*)d_in[9];
  float* out = (float*)d_out;

  char* base = (char*)d_ws;
  size_t off = 0;
  unsigned short* hbuf = (unsigned short*)(base + off); off += (size_t)N * D * 2;  // bf16
  unsigned short* abuf = (unsigned short*)(base + off); off += (size_t)N * D * 2;  // bf16
  unsigned short* Wf1 = (unsigned short*)(base + off);  off += (size_t)D * D * 2;
  unsigned short* Wf2 = (unsigned short*)(base + off);  off += (size_t)D * D * 2;
  int*   degc = (int*)(base + off);   off += (size_t)N * 4;
  float* dinv = (float*)(base + off); off += (size_t)N * 4;
  int*   offs = (int*)(base + off);   off += (size_t)(N + 4) * 4;
  int*   curs = (int*)(base + off);   off += (size_t)N * 4;
  int2*  epair = (int2*)(base + off); off += (size_t)(E + N) * 8;
  float* partial = (float*)(base + off); off += (size_t)BN_BLOCKS * 512 * 4;  // 1 MB
  float* bnsum = (float*)(base + off); off += (size_t)D * 4;
  float* bnsq  = (float*)(base + off); off += (size_t)D * 4;
  float* sc1 = (float*)(base + off);  off += (size_t)D * 4;
  float* sh1 = (float*)(base + off);  off += (size_t)D * 4;
  float* sc2 = (float*)(base + off);  off += (size_t)D * 4;
  float* sh2 = (float*)(base + off);  off += (size_t)D * 4;
  int*   bsum = (int*)(base + off);   off += 256 * 4;
  int*   flag = (int*)(base + off);   off += 16;

  // ---- W repack (independent of graph build) ----
  k_wfrag<<<128, 64, 0, stream>>>(W1, Wf1);
  k_wfrag<<<128, 64, 0, stream>>>(W2, Wf2);

  // ---- graph structure ----
  hipMemsetAsync(degc, 0, (size_t)N * 4, stream);
  k_detect<<<1, 64, 0, stream>>>(ei, flag);
  k_count<<<(E + 255) / 256, 256, 0, stream>>>(ei, flag, degc);
  k_scan_partial<<<NB, 256, 0, stream>>>(degc, bsum, dinv);
  k_scan_block<<<1, 256, 0, stream>>>(bsum);
  k_scan_final<<<NB, 256, 0, stream>>>(degc, bsum, dinv, offs, curs, epair);
  k_fill_edges<<<(E + 255) / 256, 256, 0, stream>>>(ei, flag, dinv, curs, epair);

  // ---- layer 1: GEMM -> aggregate(bf16) -> stats (apply fused into L2 GEMM) ----
  k_gemm<false, false><<<GB, 256, 0, stream>>>(x, Wf1, hbuf, nullptr, nullptr);
  k_agg<<<(N + 3) / 4, 256, 0, stream>>>(hbuf, offs, epair, b1, abuf);
  hipMemsetAsync(bnsum, 0, 2 * (size_t)D * 4, stream);  // bnsum+bnsq contiguous
  k_bnpart<<<BN_BLOCKS, 256, 0, stream>>>(abuf, partial);
  k_bnred<<<16, 256, 0, stream>>>(partial, bnsum, bnsq);
  k_bnfinal<<<1, 256, 0, stream>>>(bnsum, bnsq, g1, be1, sc1, sh1);

  // ---- layer 2: fused(BN1+ReLU) GEMM -> aggregate(bf16) -> stats -> apply ----
  k_gemm<true, true><<<GB, 256, 0, stream>>>(abuf, Wf2, hbuf, sc1, sh1);
  k_agg<<<(N + 3) / 4, 256, 0, stream>>>(hbuf, offs, epair, b2, abuf);
  hipMemsetAsync(bnsum, 0, 2 * (size_t)D * 4, stream);
  k_bnpart<<<BN_BLOCKS, 256, 0, stream>>>(abuf, partial);
  k_bnred<<<16, 256, 0, stream>>>(partial, bnsum, bnsq);
  k_bnfinal<<<1, 256, 0, stream>>>(bnsum, bnsq, g2, be2, sc2, sh2);
  k_bnapply<<<512, 256, 0, stream>>>(abuf, out, sc2, sh2);
}